// Round 8
// baseline (281.715 us; speedup 1.0000x reference)
//
#include <hip/hip_runtime.h>
#include <math.h>

typedef unsigned short u16;
typedef unsigned char  u8;
typedef unsigned int   u32;
typedef __attribute__((ext_vector_type(8))) short bf16x8;
typedef __attribute__((ext_vector_type(4))) float f32x4;

#define NSEQ   1024
#define DMODEL 1024
#define ZTOT   64
#define LOG2E  1.4426950408889634f

typedef const __attribute__((address_space(1))) void* gp1;
typedef __attribute__((address_space(3))) void* lp3;

__device__ __forceinline__ void gload16(const void* g, void* l) {
    __builtin_amdgcn_global_load_lds((gp1)g, (lp3)l, 16, 0, 0);
}

__device__ __forceinline__ u16 f2bf(float f) {
    u32 u = __builtin_bit_cast(u32, f);
    return (u16)((u + 0x7FFFu + ((u >> 16) & 1u)) >> 16);
}

// HW packed f32->bf16 (RNE), 2 values -> 1 dword
__device__ __forceinline__ u32 cvt_pk_bf16(float a, float b) {
    u32 r;
    asm("v_cvt_pk_bf16_f32 %0, %1, %2" : "=v"(r) : "v"(a), "v"(b));
    return r;
}

// ---------------------------------------------------------------------------
// fp32 -> bf16 elementwise
// ---------------------------------------------------------------------------
__launch_bounds__(256)
__global__ void cvt_bf16(const float* __restrict__ in, u16* __restrict__ out) {
    int i = (blockIdx.x * 256 + threadIdx.x) * 4;
    float4 v = *(const float4*)(in + i);
    uint2 o;
    o.x = cvt_pk_bf16(v.x, v.y);
    o.y = cvt_pk_bf16(v.z, v.w);
    *(uint2*)(out + i) = o;
}

struct P5 { const float* in[5]; u16* out[5]; };
__launch_bounds__(256)
__global__ void cvt_bf16_5(P5 p) {
    int which = blockIdx.x >> 10;
    int blk   = blockIdx.x & 1023;
    int i = (blk * 256 + threadIdx.x) * 4;
    float4 v = *(const float4*)(p.in[which] + i);
    uint2 o;
    o.x = cvt_pk_bf16(v.x, v.y);
    o.y = cvt_pk_bf16(v.z, v.w);
    *(uint2*)(p.out[which] + i) = o;
}

// sign(sum |row|) over 64 bf16 -> 0/1 ; grid 512: first half Kh->km, second Qh->qm
__launch_bounds__(256)
__global__ void rowmask2_bf(const u16* __restrict__ Kh, const u16* __restrict__ Qh,
                            float* __restrict__ km, float* __restrict__ qm) {
    int b = blockIdx.x;
    const u16* T = (b < 256) ? Kh : Qh;
    float* o = (b < 256) ? km : qm;
    int r = (b & 255) * 256 + threadIdx.x;
    const uint4* p = (const uint4*)(T + (size_t)r * 64);
    u32 acc = 0;
    #pragma unroll
    for (int i = 0; i < 8; i++) {
        uint4 q = p[i];
        acc |= (q.x | q.y | q.z | q.w) & 0x7fff7fffu;
    }
    o[r] = acc ? 1.f : 0.f;
}

// Vt[z][dh][tok] &= (km[z][tok] != 0)
__launch_bounds__(256)
__global__ void vt_km(u16* __restrict__ Vt, const float* __restrict__ km) {
    int idx = blockIdx.x * 256 + threadIdx.x;  // uint4 index (8 bf16)
    int e0 = idx * 8;
    int z = e0 >> 16;
    int tok = e0 & 1023;
    float4 ka = *(const float4*)(km + z * 1024 + tok);
    float4 kb = *(const float4*)(km + z * 1024 + tok + 4);
    uint4 v = *(uint4*)(Vt + e0);
    u32 m;
    m = (ka.x != 0.f ? 0x0000FFFFu : 0u) | (ka.y != 0.f ? 0xFFFF0000u : 0u); v.x &= m;
    m = (ka.z != 0.f ? 0x0000FFFFu : 0u) | (ka.w != 0.f ? 0xFFFF0000u : 0u); v.y &= m;
    m = (kb.x != 0.f ? 0x0000FFFFu : 0u) | (kb.y != 0.f ? 0xFFFF0000u : 0u); v.z &= m;
    m = (kb.z != 0.f ? 0x0000FFFFu : 0u) | (kb.w != 0.f ? 0xFFFF0000u : 0u); v.w &= m;
    *(uint4*)(Vt + e0) = v;
}

// ---------------------------------------------------------------------------
// Fused QKV projection GEMM, m97 structure: BM=BN=128, BK=32, 4 waves.
// grid (24, 32): bx>>3 selects {Q, K, V}.
// ---------------------------------------------------------------------------
__launch_bounds__(256)
__global__ void gemm_qkv(const u16* __restrict__ A,
                         const u16* __restrict__ Wq, const u16* __restrict__ Wk,
                         const u16* __restrict__ Wv,
                         u16* __restrict__ Qh, u16* __restrict__ Kh, u16* __restrict__ Vt)
{
    __shared__ __align__(16) u16 lA[2][128 * 32];
    __shared__ __align__(16) u16 lB[2][128 * 32];
    const int tid = threadIdx.x, lane = tid & 63, w = tid >> 6;
    const int frow = lane & 15, koct = lane >> 4;
    const int sel = blockIdx.x >> 3;
    const int col0 = (blockIdx.x & 7) * 128, row0 = blockIdx.y * 128;
    const u16* B = (sel == 0) ? Wq : (sel == 1) ? Wk : Wv;
    const int wrow = (w >> 1) * 64, wcol = (w & 1) * 64;
    f32x4 acc[4][4] = {};

    auto stage = [&](int buf, int k0) {
        #pragma unroll
        for (int i = 0; i < 2; i++) {
            int p = tid + i * 256;
            int row = p >> 2, sl = p & 3, ssl = sl ^ ((row >> 1) & 3);
            gload16(A + (size_t)(row0 + row) * 1024 + k0 + ssl * 8, (char*)lA[buf] + p * 16);
        }
        #pragma unroll
        for (int i = 0; i < 2; i++) {
            int p = tid + i * 256;
            int row = p >> 2, sl = p & 3, ssl = sl ^ ((row >> 1) & 3);
            gload16(B + (size_t)(col0 + row) * 1024 + k0 + ssl * 8, (char*)lB[buf] + p * 16);
        }
    };

    stage(0, 0);
    __syncthreads();
    int buf = 0;
    for (int k0 = 0; k0 < 1024; k0 += 32) {
        if (k0 + 32 < 1024) stage(buf ^ 1, k0 + 32);
        __builtin_amdgcn_s_setprio(1);
        bf16x8 af[4], bf[4];
        #pragma unroll
        for (int i = 0; i < 4; i++) {
            int r = wrow + i * 16 + frow;
            int sl = koct ^ ((r >> 1) & 3);
            af[i] = *(const bf16x8*)((const char*)lA[buf] + r * 64 + sl * 16);
        }
        #pragma unroll
        for (int j = 0; j < 4; j++) {
            int r = wcol + j * 16 + frow;
            int sl = koct ^ ((r >> 1) & 3);
            bf[j] = *(const bf16x8*)((const char*)lB[buf] + r * 64 + sl * 16);
        }
        #pragma unroll
        for (int i = 0; i < 4; i++)
            #pragma unroll
            for (int j = 0; j < 4; j++)
                acc[i][j] = __builtin_amdgcn_mfma_f32_16x16x32_bf16(af[i], bf[j], acc[i][j], 0, 0, 0);
        __builtin_amdgcn_s_setprio(0);
        __syncthreads();
        buf ^= 1;
    }

    if (sel < 2) {
        const float scale = (sel == 0) ? 0.125f * LOG2E : 1.0f;
        u16* outp = (sel == 0) ? Qh : Kh;
        #pragma unroll
        for (int i = 0; i < 4; i++)
            #pragma unroll
            for (int j = 0; j < 4; j++)
                #pragma unroll
                for (int q = 0; q < 4; q++) {
                    int r = row0 + wrow + i * 16 + koct * 4 + q;
                    int c = col0 + wcol + j * 16 + frow;
                    float v = acc[i][j][q] * scale;
                    outp[(size_t)((c >> 6) * 4 + (r >> 10)) * 65536 +
                         (size_t)(r & 1023) * 64 + (c & 63)] = f2bf(v);
                }
    } else {
        #pragma unroll
        for (int i = 0; i < 4; i++) {
            int r0 = row0 + wrow + i * 16 + koct * 4;   // token base (mult of 4)
            #pragma unroll
            for (int j = 0; j < 4; j++) {
                int c = col0 + wcol + j * 16 + frow;    // channel
                int z = (c >> 6) * 4 + (r0 >> 10);
                uint2 pk;
                pk.x = cvt_pk_bf16(acc[i][j][0], acc[i][j][1]);
                pk.y = cvt_pk_bf16(acc[i][j][2], acc[i][j][3]);
                *(uint2*)(Vt + (size_t)z * 65536 + (size_t)(c & 63) * 1024 + (r0 & 1023)) = pk;
            }
        }
    }
}

// ---------------------------------------------------------------------------
// bf16 MFMA GEMM for FFN. MODE 2: +bias+relu bf16. MODE 3: +bias f32.
// ---------------------------------------------------------------------------
template <int MODE>
__launch_bounds__(256)
__global__ void gemm_bt(const u16* __restrict__ A, const u16* __restrict__ B,
                        const float* __restrict__ bias, void* __restrict__ outp)
{
    __shared__ __align__(16) u16 lA[2][128 * 64];
    __shared__ __align__(16) u16 lB[2][64 * 64];
    const int tid = threadIdx.x, lane = tid & 63, w = tid >> 6;
    const int frow = lane & 15, koct = lane >> 4;
    const int col0 = blockIdx.x * 64, row0 = blockIdx.y * 128;
    const int wrow = (w >> 1) * 64, wcol = (w & 1) * 32;
    f32x4 acc[4][2] = {};

    auto stage = [&](int buf, int k0) {
        #pragma unroll
        for (int i = 0; i < 4; i++) {
            int p = tid + i * 256;
            int row = p >> 3, sl = p & 7, ssl = sl ^ (row & 7);
            gload16(A + (size_t)(row0 + row) * 1024 + k0 + ssl * 8, (char*)lA[buf] + p * 16);
        }
        #pragma unroll
        for (int i = 0; i < 2; i++) {
            int p = tid + i * 256;
            int row = p >> 3, sl = p & 7, ssl = sl ^ (row & 7);
            gload16(B + (size_t)(col0 + row) * 1024 + k0 + ssl * 8, (char*)lB[buf] + p * 16);
        }
    };

    stage(0, 0);
    __syncthreads();
    int buf = 0;
    for (int k0 = 0; k0 < 1024; k0 += 64) {
        if (k0 + 64 < 1024) stage(buf ^ 1, k0 + 64);
        __builtin_amdgcn_s_setprio(1);
        #pragma unroll
        for (int ks = 0; ks < 2; ks++) {
            bf16x8 af[4], bf2[2];
            #pragma unroll
            for (int i = 0; i < 4; i++) {
                int r = wrow + i * 16 + frow;
                int sl = (ks * 4 + koct) ^ (r & 7);
                af[i] = *(const bf16x8*)((const char*)lA[buf] + r * 128 + sl * 16);
            }
            #pragma unroll
            for (int j = 0; j < 2; j++) {
                int r = wcol + j * 16 + frow;
                int sl = (ks * 4 + koct) ^ (r & 7);
                bf2[j] = *(const bf16x8*)((const char*)lB[buf] + r * 128 + sl * 16);
            }
            #pragma unroll
            for (int i = 0; i < 4; i++)
                #pragma unroll
                for (int j = 0; j < 2; j++)
                    acc[i][j] = __builtin_amdgcn_mfma_f32_16x16x32_bf16(af[i], bf2[j], acc[i][j], 0, 0, 0);
        }
        __builtin_amdgcn_s_setprio(0);
        __syncthreads();
        buf ^= 1;
    }

    #pragma unroll
    for (int i = 0; i < 4; i++)
        #pragma unroll
        for (int j = 0; j < 2; j++)
            #pragma unroll
            for (int q = 0; q < 4; q++) {
                int r = row0 + wrow + i * 16 + koct * 4 + q;
                int c = col0 + wcol + j * 16 + frow;
                float v = acc[i][j][q] + bias[c];
                if constexpr (MODE == 2) {
                    v = fmaxf(v, 0.f);
                    ((u16*)outp)[(size_t)r * 1024 + c] = f2bf(v);
                } else {
                    ((float*)outp)[(size_t)r * 1024 + c] = v;
                }
            }
}

// ---------------------------------------------------------------------------
// Pass 1: partial[zg][n][m] = sum_{z in zg*16..+16} exp2(s'_znm) * km01(z,m)
// Wave-independent: each wave owns a 32n x 32m x 16z quadrant; no LDS, no
// barriers; Q/K fragments direct from L2. grid 1024 x 256.
// XCD c owns {zg = c>>1, m-half = c&1} -> ~3MB L2 working set.
// ---------------------------------------------------------------------------
__launch_bounds__(256)
__global__ void attn_pass1(const u16* __restrict__ Qh, const u16* __restrict__ Kh,
                           const float* __restrict__ km, float* __restrict__ partial)
{
    const int tid = threadIdx.x, lane = tid & 63, w = tid >> 6;
    const int frow = lane & 15, koct = lane >> 4;
    const int bid = blockIdx.x;
    const int c = bid & 7;
    const int local = (bid >> 3) * 4 + w;            // 0..511
    const int zg = c >> 1;
    const int m0 = ((c & 1) * 16 + (local & 15)) * 32;
    const int n0 = (local >> 4) * 32;

    f32x4 ssum[2][2] = {};
    const int z0 = zg * 16;
    for (int z = z0; z < z0 + 16; z++) {
        const u16* Qz = Qh + (size_t)z * 65536;
        const u16* Kz = Kh + (size_t)z * 65536;
        f32x4 s[2][2] = {};
        __builtin_amdgcn_s_setprio(1);
        #pragma unroll
        for (int ks = 0; ks < 2; ks++) {
            bf16x8 a[2], kb[2];
            #pragma unroll
            for (int i = 0; i < 2; i++)
                a[i] = *(const bf16x8*)(Qz + (size_t)(n0 + i * 16 + frow) * 64 + ks * 32 + koct * 8);
            #pragma unroll
            for (int j = 0; j < 2; j++)
                kb[j] = *(const bf16x8*)(Kz + (size_t)(m0 + j * 16 + frow) * 64 + ks * 32 + koct * 8);
            #pragma unroll
            for (int i = 0; i < 2; i++)
                #pragma unroll
                for (int j = 0; j < 2; j++)
                    s[i][j] = __builtin_amdgcn_mfma_f32_16x16x32_bf16(kb[j], a[i], s[i][j], 0, 0, 0);
        }
        __builtin_amdgcn_s_setprio(0);
        f32x4 km4[2];
        #pragma unroll
        for (int j = 0; j < 2; j++)
            km4[j] = *(const f32x4*)(km + z * NSEQ + m0 + j * 16 + koct * 4);
        #pragma unroll
        for (int j = 0; j < 2; j++)
            #pragma unroll
            for (int i = 0; i < 2; i++)
                #pragma unroll
                for (int q = 0; q < 4; q++)
                    ssum[i][j][q] += __builtin_amdgcn_exp2f(s[i][j][q]) * km4[j][q];
    }
    #pragma unroll
    for (int i = 0; i < 2; i++)
        #pragma unroll
        for (int j = 0; j < 2; j++) {
            int ng = n0 + i * 16 + frow;
            int mg = m0 + j * 16 + koct * 4;
            *(f32x4*)(partial + (size_t)zg * 1048576 + (size_t)ng * NSEQ + mg) = ssum[i][j];
        }
}

// invS = 1 / (p0+p1+p2+p3)
__launch_bounds__(256)
__global__ void sum_inv(const float* __restrict__ p, float* __restrict__ invS) {
    int i = (blockIdx.x * 256 + threadIdx.x) * 4;
    float4 a = *(const float4*)(p + i);
    float4 b = *(const float4*)(p + 1048576 + i);
    float4 c = *(const float4*)(p + 2097152 + i);
    float4 d = *(const float4*)(p + 3145728 + i);
    float4 r;
    float s;
    s = a.x + b.x + c.x + d.x; r.x = s > 0.f ? 1.f / s : 0.f;
    s = a.y + b.y + c.y + d.y; r.y = s > 0.f ? 1.f / s : 0.f;
    s = a.z + b.z + c.z + d.z; r.z = s > 0.f ? 1.f / s : 0.f;
    s = a.w + b.w + c.w + d.w; r.w = s > 0.f ? 1.f / s : 0.f;
    *(float4*)(invS + i) = r;
}

// ---------------------------------------------------------------------------
// Pass 2: per z, out[z,n,:] = sum_m (exp2(s')*invS) V'[m,:]   (V' = V*km)
// Wave-independent: each wave owns (z, 32 n-rows); K/V direct from L2 (each
// tile read once per wave); wave-private lP stripe; ZERO barriers.
// grid 512 x 256, XCD c owns z in {8c..8c+7} (K/V L2-resident).
// ---------------------------------------------------------------------------
__launch_bounds__(256)
__global__ void attn_pass2(const u16* __restrict__ Qh, const u16* __restrict__ Kh,
                           const u16* __restrict__ Vt,
                           const float* __restrict__ qm, const float* __restrict__ invS,
                           const u8* __restrict__ pad, float* __restrict__ attn)
{
    __shared__ __align__(16) u16 lP[4][32 * 64];   // 4KB per wave
    const int tid = threadIdx.x, lane = tid & 63, w = tid >> 6;
    const int frow = lane & 15, koct = lane >> 4;
    const int bid = blockIdx.x;
    const int local = (bid >> 3) * 4 + w;          // 0..255
    const int z  = (bid & 7) * 8 + (local >> 5);
    const int n0 = (local & 31) * 32;
    const int hh = z >> 2, bb = z & 3;
    char* lPw = (char*)&lP[w][0];

    const u16* Kz = Kh + (size_t)z * 65536;
    const u16* Vz = Vt + (size_t)z * 65536;

    // Q fragments (loop-invariant)
    bf16x8 aq[2][2];
    #pragma unroll
    for (int i = 0; i < 2; i++)
        #pragma unroll
        for (int ks = 0; ks < 2; ks++)
            aq[i][ks] = *(const bf16x8*)(Qh + (size_t)z * 65536 +
                                         (size_t)(n0 + i * 16 + frow) * 64 + ks * 32 + koct * 8);

    f32x4 oacc[2][4] = {};

    for (int mt = 0; mt < 16; mt++) {
        const int m0 = mt * 64;
        // scores: s[i][j], n = n0+i*16+frow, m = m0+j*16+koct*4+q
        f32x4 s[2][4] = {};
        __builtin_amdgcn_s_setprio(1);
        #pragma unroll
        for (int ks = 0; ks < 2; ks++) {
            bf16x8 kb[4];
            #pragma unroll
            for (int j = 0; j < 4; j++)
                kb[j] = *(const bf16x8*)(Kz + (size_t)(m0 + j * 16 + frow) * 64 + ks * 32 + koct * 8);
            #pragma unroll
            for (int i = 0; i < 2; i++)
                #pragma unroll
                for (int j = 0; j < 4; j++)
                    s[i][j] = __builtin_amdgcn_mfma_f32_16x16x32_bf16(kb[j], aq[i][ks], s[i][j], 0, 0, 0);
        }
        __builtin_amdgcn_s_setprio(0);
        // P = exp2(s)*invS -> bf16 pairs -> wave-private lP
        #pragma unroll
        for (int i = 0; i < 2; i++) {
            const size_t inv_base = (size_t)(n0 + i * 16 + frow) * NSEQ;
            const int r = i * 16 + frow;
            #pragma unroll
            for (int j = 0; j < 4; j++) {
                int mg = m0 + j * 16 + koct * 4;
                f32x4 iv = *(const f32x4*)(invS + inv_base + mg);
                float p0 = __builtin_amdgcn_exp2f(s[i][j][0]) * iv[0];
                float p1 = __builtin_amdgcn_exp2f(s[i][j][1]) * iv[1];
                float p2 = __builtin_amdgcn_exp2f(s[i][j][2]) * iv[2];
                float p3 = __builtin_amdgcn_exp2f(s[i][j][3]) * iv[3];
                uint2 pk;
                pk.x = cvt_pk_bf16(p0, p1);
                pk.y = cvt_pk_bf16(p2, p3);
                int slot = (j * 2 + (koct >> 1)) ^ (r & 7);
                *(uint2*)(lPw + r * 128 + slot * 16 + (koct & 1) * 8) = pk;
            }
        }
        // PV: A = P stripe rows, B = Vt rows (d-major), V direct from L2
        __builtin_amdgcn_s_setprio(1);
        #pragma unroll
        for (int ks = 0; ks < 2; ks++) {
            bf16x8 vb[4];
            #pragma unroll
            for (int dj = 0; dj < 4; dj++)
                vb[dj] = *(const bf16x8*)(Vz + (size_t)(dj * 16 + frow) * 1024 + m0 + ks * 32 + koct * 8);
            #pragma unroll
            for (int i = 0; i < 2; i++) {
                const int r = i * 16 + frow;
                int sl = (ks * 4 + koct) ^ (r & 7);
                bf16x8 pa = *(const bf16x8*)(lPw + r * 128 + sl * 16);
                #pragma unroll
                for (int dj = 0; dj < 4; dj++)
                    oacc[i][dj] = __builtin_amdgcn_mfma_f32_16x16x32_bf16(pa, vb[dj], oacc[i][dj], 0, 0, 0);
            }
        }
        __builtin_amdgcn_s_setprio(0);
    }

    #pragma unroll
    for (int i = 0; i < 2; i++)
        #pragma unroll
        for (int q = 0; q < 4; q++) {
            int ns = n0 + i * 16 + koct * 4 + q;
            float f = qm[z * NSEQ + ns] * (pad[bb * NSEQ + ns] ? 0.f : 1.f);
            #pragma unroll
            for (int dj = 0; dj < 4; dj++) {
                int d = dj * 16 + frow;
                attn[(size_t)(bb * NSEQ + ns) * DMODEL + hh * 64 + d] = oacc[i][dj][q] * f;
            }
        }
}

// ---------------------------------------------------------------------------
// LayerNorm over last dim (1024), one block per row.
// ---------------------------------------------------------------------------
__launch_bounds__(256)
__global__ void ln_kernel(const float* __restrict__ A, const float* __restrict__ Bv,
                          const float* __restrict__ g, const float* __restrict__ beta,
                          const u8* __restrict__ pad, int mode,
                          float* __restrict__ out, u16* __restrict__ outb)
{
    const int row = blockIdx.x, tid = threadIdx.x;
    const int lane = tid & 63, wv = tid >> 6;
    const float valid = pad[row] ? 0.f : 1.f;
    __shared__ float red[4];

    float4 va = *(const float4*)(A + (size_t)row * 1024 + tid * 4);
    float4 vb = *(const float4*)(Bv + (size_t)row * 1024 + tid * 4);
    float v[4];
    if (mode == 0) {
        v[0] = va.x + vb.x; v[1] = va.y + vb.y; v[2] = va.z + vb.z; v[3] = va.w + vb.w;
    } else {
        v[0] = va.x * valid + vb.x; v[1] = va.y * valid + vb.y;
        v[2] = va.z * valid + vb.z; v[3] = va.w * valid + vb.w;
    }
    float s = v[0] + v[1] + v[2] + v[3];
    #pragma unroll
    for (int off = 32; off > 0; off >>= 1) s += __shfl_down(s, off, 64);
    if (lane == 0) red[wv] = s;
    __syncthreads();
    float mean = (red[0] + red[1] + red[2] + red[3]) * (1.f / 1024.f);
    float sq = 0.f;
    #pragma unroll
    for (int k = 0; k < 4; k++) { float d = v[k] - mean; sq += d * d; }
    __syncthreads();
    #pragma unroll
    for (int off = 32; off > 0; off >>= 1) sq += __shfl_down(sq, off, 64);
    if (lane == 0) red[wv] = sq;
    __syncthreads();
    float var = (red[0] + red[1] + red[2] + red[3]) * (1.f / 1024.f);
    float rstd = rsqrtf(var + 1e-5f);
    float osc = (mode == 0) ? 1.f : valid;
    #pragma unroll
    for (int k = 0; k < 4; k++) {
        int c = tid * 4 + k;
        float o = ((v[k] - mean) * rstd * g[c] + beta[c]) * osc;
        out[(size_t)row * 1024 + c] = o;
        if (outb) outb[(size_t)row * 1024 + c] = f2bf(o);
    }
}

// ---------------------------------------------------------------------------
extern "C" void kernel_launch(void* const* d_in, const int* in_sizes, int n_in,
                              void* d_out, int out_size, void* d_ws, size_t ws_size,
                              hipStream_t stream)
{
    const float* x   = (const float*)d_in[0];
    const u8*    pad = (const u8*)d_in[1];
    const float* Wq  = (const float*)d_in[2];
    const float* Wk  = (const float*)d_in[3];
    const float* Wv  = (const float*)d_in[4];
    const float* W1  = (const float*)d_in[5];
    const float* b1  = (const float*)d_in[6];
    const float* W2  = (const float*)d_in[7];
    const float* b2  = (const float*)d_in[8];
    const float* g1  = (const float*)d_in[9];
    const float* be1 = (const float*)d_in[10];
    const float* g2  = (const float*)d_in[11];
    const float* be2 = (const float*)d_in[12];
    float* out = (float*)d_out;

    // workspace (~99 MB)
    u16* xb   = (u16*)d_ws;
    u16* Wqb  = xb   + 4194304;
    u16* Wkb  = Wqb  + 1048576;
    u16* Wvb  = Wkb  + 1048576;
    u16* W1b  = Wvb  + 1048576;
    u16* W2b  = W1b  + 1048576;
    u16* Qh   = W2b  + 1048576;        // [z][n][dh]
    u16* Kh   = Qh   + 4194304;        // [z][n][dh]
    u16* Vt   = Kh   + 4194304;        // [z][dh][n]  (km applied by vt_km)
    u16* hb   = Vt   + 4194304;
    u16* ff1b = hb   + 4194304;
    float* km      = (float*)(ff1b + 4194304);
    float* qm      = km      + 65536;
    float* partial = qm      + 65536;           // 4M f32
    float* invS    = partial + 4194304;         // 1M f32
    float* h       = invS    + 1048576;         // 4M f32

    cvt_bf16<<<4096, 256, 0, stream>>>(x, xb);
    P5 p5;
    p5.in[0] = Wq; p5.in[1] = Wk; p5.in[2] = Wv; p5.in[3] = W1; p5.in[4] = W2;
    p5.out[0] = Wqb; p5.out[1] = Wkb; p5.out[2] = Wvb; p5.out[3] = W1b; p5.out[4] = W2b;
    cvt_bf16_5<<<5120, 256, 0, stream>>>(p5);

    // fused Q/K/V projections, m97-structure 128x128 tiles
    gemm_qkv<<<dim3(24, 32), 256, 0, stream>>>(xb, Wqb, Wkb, Wvb, Qh, Kh, Vt);

    rowmask2_bf<<<512, 256, 0, stream>>>(Kh, Qh, km, qm);
    vt_km<<<4096, 256, 0, stream>>>(Vt, km);

    attn_pass1<<<1024, 256, 0, stream>>>(Qh, Kh, km, partial);
    sum_inv<<<1024, 256, 0, stream>>>(partial, invS);
    attn_pass2<<<512, 256, 0, stream>>>(Qh, Kh, Vt, qm, invS, pad, out);

    ln_kernel<<<4096, 256, 0, stream>>>(x, out, g1, be1, pad, 0, h, hb);

    gemm_bt<2><<<dim3(16, 32), 256, 0, stream>>>(hb,   W1b, b1, ff1b);
    gemm_bt<3><<<dim3(16, 32), 256, 0, stream>>>(ff1b, W2b, b2, out);

    ln_kernel<<<4096, 256, 0, stream>>>(out, h, g2, be2, pad, 1, out, nullptr);
}

// Round 9
// 202.846 us; speedup vs baseline: 1.3888x; 1.3888x over previous
//
#include <hip/hip_runtime.h>
#include <math.h>

typedef unsigned short u16;
typedef unsigned char  u8;
typedef unsigned int   u32;
typedef __attribute__((ext_vector_type(8))) short bf16x8;
typedef __attribute__((ext_vector_type(4))) float f32x4;

#define NSEQ   1024
#define DMODEL 1024
#define ZTOT   64
#define LOG2E  1.4426950408889634f

typedef const __attribute__((address_space(1))) void* gp1;
typedef __attribute__((address_space(3))) void* lp3;

__device__ __forceinline__ void gload16(const void* g, void* l) {
    __builtin_amdgcn_global_load_lds((gp1)g, (lp3)l, 16, 0, 0);
}

__device__ __forceinline__ u16 f2bf(float f) {
    u32 u = __builtin_bit_cast(u32, f);
    return (u16)((u + 0x7FFFu + ((u >> 16) & 1u)) >> 16);
}

// HW packed f32->bf16 (RNE), 2 values -> 1 dword
__device__ __forceinline__ u32 cvt_pk_bf16(float a, float b) {
    u32 r;
    asm("v_cvt_pk_bf16_f32 %0, %1, %2" : "=v"(r) : "v"(a), "v"(b));
    return r;
}

// ---------------------------------------------------------------------------
// fp32 -> bf16 elementwise
// ---------------------------------------------------------------------------
__launch_bounds__(256)
__global__ void cvt_bf16(const float* __restrict__ in, u16* __restrict__ out) {
    int i = (blockIdx.x * 256 + threadIdx.x) * 4;
    float4 v = *(const float4*)(in + i);
    uint2 o;
    o.x = cvt_pk_bf16(v.x, v.y);
    o.y = cvt_pk_bf16(v.z, v.w);
    *(uint2*)(out + i) = o;
}

struct P5 { const float* in[5]; u16* out[5]; };
__launch_bounds__(256)
__global__ void cvt_bf16_5(P5 p) {
    int which = blockIdx.x >> 10;
    int blk   = blockIdx.x & 1023;
    int i = (blk * 256 + threadIdx.x) * 4;
    float4 v = *(const float4*)(p.in[which] + i);
    uint2 o;
    o.x = cvt_pk_bf16(v.x, v.y);
    o.y = cvt_pk_bf16(v.z, v.w);
    *(uint2*)(p.out[which] + i) = o;
}

// sign(sum |row|) over 64 bf16 -> 0/1 ; grid 512: first half Kh->km, second Qh->qm
__launch_bounds__(256)
__global__ void rowmask2_bf(const u16* __restrict__ Kh, const u16* __restrict__ Qh,
                            float* __restrict__ km, float* __restrict__ qm) {
    int b = blockIdx.x;
    const u16* T = (b < 256) ? Kh : Qh;
    float* o = (b < 256) ? km : qm;
    int r = (b & 255) * 256 + threadIdx.x;
    const uint4* p = (const uint4*)(T + (size_t)r * 64);
    u32 acc = 0;
    #pragma unroll
    for (int i = 0; i < 8; i++) {
        uint4 q = p[i];
        acc |= (q.x | q.y | q.z | q.w) & 0x7fff7fffu;
    }
    o[r] = acc ? 1.f : 0.f;
}

// Vt[z][dh][tok] &= (km[z][tok] != 0)
__launch_bounds__(256)
__global__ void vt_km(u16* __restrict__ Vt, const float* __restrict__ km) {
    int idx = blockIdx.x * 256 + threadIdx.x;  // uint4 index (8 bf16)
    int e0 = idx * 8;
    int z = e0 >> 16;
    int tok = e0 & 1023;
    float4 ka = *(const float4*)(km + z * 1024 + tok);
    float4 kb = *(const float4*)(km + z * 1024 + tok + 4);
    uint4 v = *(uint4*)(Vt + e0);
    u32 m;
    m = (ka.x != 0.f ? 0x0000FFFFu : 0u) | (ka.y != 0.f ? 0xFFFF0000u : 0u); v.x &= m;
    m = (ka.z != 0.f ? 0x0000FFFFu : 0u) | (ka.w != 0.f ? 0xFFFF0000u : 0u); v.y &= m;
    m = (kb.x != 0.f ? 0x0000FFFFu : 0u) | (kb.y != 0.f ? 0xFFFF0000u : 0u); v.z &= m;
    m = (kb.z != 0.f ? 0x0000FFFFu : 0u) | (kb.w != 0.f ? 0xFFFF0000u : 0u); v.w &= m;
    *(uint4*)(Vt + e0) = v;
}

// ---------------------------------------------------------------------------
// Fused QKV projection GEMM, m97 structure: BM=BN=128, BK=32, 4 waves.
// grid (24, 32): bx>>3 selects {Q, K, V}.
// ---------------------------------------------------------------------------
__launch_bounds__(256)
__global__ void gemm_qkv(const u16* __restrict__ A,
                         const u16* __restrict__ Wq, const u16* __restrict__ Wk,
                         const u16* __restrict__ Wv,
                         u16* __restrict__ Qh, u16* __restrict__ Kh, u16* __restrict__ Vt)
{
    __shared__ __align__(16) u16 lA[2][128 * 32];
    __shared__ __align__(16) u16 lB[2][128 * 32];
    const int tid = threadIdx.x, lane = tid & 63, w = tid >> 6;
    const int frow = lane & 15, koct = lane >> 4;
    const int sel = blockIdx.x >> 3;
    const int col0 = (blockIdx.x & 7) * 128, row0 = blockIdx.y * 128;
    const u16* B = (sel == 0) ? Wq : (sel == 1) ? Wk : Wv;
    const int wrow = (w >> 1) * 64, wcol = (w & 1) * 64;
    f32x4 acc[4][4] = {};

    auto stage = [&](int buf, int k0) {
        #pragma unroll
        for (int i = 0; i < 2; i++) {
            int p = tid + i * 256;
            int row = p >> 2, sl = p & 3, ssl = sl ^ ((row >> 1) & 3);
            gload16(A + (size_t)(row0 + row) * 1024 + k0 + ssl * 8, (char*)lA[buf] + p * 16);
        }
        #pragma unroll
        for (int i = 0; i < 2; i++) {
            int p = tid + i * 256;
            int row = p >> 2, sl = p & 3, ssl = sl ^ ((row >> 1) & 3);
            gload16(B + (size_t)(col0 + row) * 1024 + k0 + ssl * 8, (char*)lB[buf] + p * 16);
        }
    };

    stage(0, 0);
    __syncthreads();
    int buf = 0;
    for (int k0 = 0; k0 < 1024; k0 += 32) {
        if (k0 + 32 < 1024) stage(buf ^ 1, k0 + 32);
        __builtin_amdgcn_s_setprio(1);
        bf16x8 af[4], bf[4];
        #pragma unroll
        for (int i = 0; i < 4; i++) {
            int r = wrow + i * 16 + frow;
            int sl = koct ^ ((r >> 1) & 3);
            af[i] = *(const bf16x8*)((const char*)lA[buf] + r * 64 + sl * 16);
        }
        #pragma unroll
        for (int j = 0; j < 4; j++) {
            int r = wcol + j * 16 + frow;
            int sl = koct ^ ((r >> 1) & 3);
            bf[j] = *(const bf16x8*)((const char*)lB[buf] + r * 64 + sl * 16);
        }
        #pragma unroll
        for (int i = 0; i < 4; i++)
            #pragma unroll
            for (int j = 0; j < 4; j++)
                acc[i][j] = __builtin_amdgcn_mfma_f32_16x16x32_bf16(af[i], bf[j], acc[i][j], 0, 0, 0);
        __builtin_amdgcn_s_setprio(0);
        __syncthreads();
        buf ^= 1;
    }

    if (sel < 2) {
        const float scale = (sel == 0) ? 0.125f * LOG2E : 1.0f;
        u16* outp = (sel == 0) ? Qh : Kh;
        #pragma unroll
        for (int i = 0; i < 4; i++)
            #pragma unroll
            for (int j = 0; j < 4; j++)
                #pragma unroll
                for (int q = 0; q < 4; q++) {
                    int r = row0 + wrow + i * 16 + koct * 4 + q;
                    int c = col0 + wcol + j * 16 + frow;
                    float v = acc[i][j][q] * scale;
                    outp[(size_t)((c >> 6) * 4 + (r >> 10)) * 65536 +
                         (size_t)(r & 1023) * 64 + (c & 63)] = f2bf(v);
                }
    } else {
        #pragma unroll
        for (int i = 0; i < 4; i++) {
            int r0 = row0 + wrow + i * 16 + koct * 4;   // token base (mult of 4)
            #pragma unroll
            for (int j = 0; j < 4; j++) {
                int c = col0 + wcol + j * 16 + frow;    // channel
                int z = (c >> 6) * 4 + (r0 >> 10);
                uint2 pk;
                pk.x = cvt_pk_bf16(acc[i][j][0], acc[i][j][1]);
                pk.y = cvt_pk_bf16(acc[i][j][2], acc[i][j][3]);
                *(uint2*)(Vt + (size_t)z * 65536 + (size_t)(c & 63) * 1024 + (r0 & 1023)) = pk;
            }
        }
    }
}

// ---------------------------------------------------------------------------
// bf16 MFMA GEMM for FFN. MODE 2: +bias+relu bf16. MODE 3: +bias f32.
// ---------------------------------------------------------------------------
template <int MODE>
__launch_bounds__(256)
__global__ void gemm_bt(const u16* __restrict__ A, const u16* __restrict__ B,
                        const float* __restrict__ bias, void* __restrict__ outp)
{
    __shared__ __align__(16) u16 lA[2][128 * 64];
    __shared__ __align__(16) u16 lB[2][64 * 64];
    const int tid = threadIdx.x, lane = tid & 63, w = tid >> 6;
    const int frow = lane & 15, koct = lane >> 4;
    const int col0 = blockIdx.x * 64, row0 = blockIdx.y * 128;
    const int wrow = (w >> 1) * 64, wcol = (w & 1) * 32;
    f32x4 acc[4][2] = {};

    auto stage = [&](int buf, int k0) {
        #pragma unroll
        for (int i = 0; i < 4; i++) {
            int p = tid + i * 256;
            int row = p >> 3, sl = p & 7, ssl = sl ^ (row & 7);
            gload16(A + (size_t)(row0 + row) * 1024 + k0 + ssl * 8, (char*)lA[buf] + p * 16);
        }
        #pragma unroll
        for (int i = 0; i < 2; i++) {
            int p = tid + i * 256;
            int row = p >> 3, sl = p & 7, ssl = sl ^ (row & 7);
            gload16(B + (size_t)(col0 + row) * 1024 + k0 + ssl * 8, (char*)lB[buf] + p * 16);
        }
    };

    stage(0, 0);
    __syncthreads();
    int buf = 0;
    for (int k0 = 0; k0 < 1024; k0 += 64) {
        if (k0 + 64 < 1024) stage(buf ^ 1, k0 + 64);
        __builtin_amdgcn_s_setprio(1);
        #pragma unroll
        for (int ks = 0; ks < 2; ks++) {
            bf16x8 af[4], bf2[2];
            #pragma unroll
            for (int i = 0; i < 4; i++) {
                int r = wrow + i * 16 + frow;
                int sl = (ks * 4 + koct) ^ (r & 7);
                af[i] = *(const bf16x8*)((const char*)lA[buf] + r * 128 + sl * 16);
            }
            #pragma unroll
            for (int j = 0; j < 2; j++) {
                int r = wcol + j * 16 + frow;
                int sl = (ks * 4 + koct) ^ (r & 7);
                bf2[j] = *(const bf16x8*)((const char*)lB[buf] + r * 128 + sl * 16);
            }
            #pragma unroll
            for (int i = 0; i < 4; i++)
                #pragma unroll
                for (int j = 0; j < 2; j++)
                    acc[i][j] = __builtin_amdgcn_mfma_f32_16x16x32_bf16(af[i], bf2[j], acc[i][j], 0, 0, 0);
        }
        __builtin_amdgcn_s_setprio(0);
        __syncthreads();
        buf ^= 1;
    }

    #pragma unroll
    for (int i = 0; i < 4; i++)
        #pragma unroll
        for (int j = 0; j < 2; j++)
            #pragma unroll
            for (int q = 0; q < 4; q++) {
                int r = row0 + wrow + i * 16 + koct * 4 + q;
                int c = col0 + wcol + j * 16 + frow;
                float v = acc[i][j][q] + bias[c];
                if constexpr (MODE == 2) {
                    v = fmaxf(v, 0.f);
                    ((u16*)outp)[(size_t)r * 1024 + c] = f2bf(v);
                } else {
                    ((float*)outp)[(size_t)r * 1024 + c] = v;
                }
            }
}

// ---------------------------------------------------------------------------
// Pass 1: partial[zg][n][m] = sum_{z in zg*16..+16} exp2(s'_znm) * km01(z,m)
// 1-D grid 1024, XCD-swizzled: XCD c owns one zg x 8 m-tiles.  (R7 staged)
// ---------------------------------------------------------------------------
__launch_bounds__(256)
__global__ void attn_pass1(const u16* __restrict__ Qh, const u16* __restrict__ Kh,
                           const float* __restrict__ km, float* __restrict__ partial)
{
    const int bid = blockIdx.x;
    const int mtzg = (bid & 7) * 8 + ((bid >> 3) & 7);   // cluster per XCD
    const int m0 = (mtzg & 15) * 64, zg = mtzg >> 4;
    const int n0 = (bid >> 6) * 64;

    __shared__ __align__(16) u16 lQ[2][64 * 64];
    __shared__ __align__(16) u16 lK[2][64 * 64];
    const int tid = threadIdx.x, lane = tid & 63, w = tid >> 6;
    const int frow = lane & 15, koct = lane >> 4;
    const int wn = (w >> 1) * 32, wm = (w & 1) * 32;
    f32x4 ssum[2][2] = {};

    auto stage = [&](int buf, int z) {
        #pragma unroll
        for (int i = 0; i < 2; i++) {
            int p = tid + i * 256;
            int row = p >> 3, sl = p & 7, ssl = sl ^ (row & 7);
            gload16(Qh + (size_t)(z * NSEQ + n0 + row) * 64 + ssl * 8, (char*)lQ[buf] + p * 16);
            gload16(Kh + (size_t)(z * NSEQ + m0 + row) * 64 + ssl * 8, (char*)lK[buf] + p * 16);
        }
    };

    const int z0 = zg * 16;
    stage(0, z0);
    __syncthreads();
    int buf = 0;
    for (int zi = 0; zi < 16; zi++) {
        const int z = z0 + zi;
        if (zi < 15) stage(buf ^ 1, z + 1);
        f32x4 km4[2];
        #pragma unroll
        for (int j = 0; j < 2; j++)
            km4[j] = *(const f32x4*)(km + z * NSEQ + m0 + wm + j * 16 + koct * 4);
        f32x4 s[2][2] = {};
        __builtin_amdgcn_s_setprio(1);
        #pragma unroll
        for (int ks = 0; ks < 2; ks++) {
            bf16x8 a[2], b2[2];
            #pragma unroll
            for (int i = 0; i < 2; i++) {
                int r = wn + i * 16 + frow;
                int sl = (ks * 4 + koct) ^ (r & 7);
                a[i] = *(const bf16x8*)((const char*)lQ[buf] + r * 128 + sl * 16);
            }
            #pragma unroll
            for (int j = 0; j < 2; j++) {
                int r = wm + j * 16 + frow;
                int sl = (ks * 4 + koct) ^ (r & 7);
                b2[j] = *(const bf16x8*)((const char*)lK[buf] + r * 128 + sl * 16);
            }
            #pragma unroll
            for (int i = 0; i < 2; i++)
                #pragma unroll
                for (int j = 0; j < 2; j++)
                    s[i][j] = __builtin_amdgcn_mfma_f32_16x16x32_bf16(b2[j], a[i], s[i][j], 0, 0, 0);
        }
        __builtin_amdgcn_s_setprio(0);
        #pragma unroll
        for (int j = 0; j < 2; j++)
            #pragma unroll
            for (int i = 0; i < 2; i++)
                #pragma unroll
                for (int q = 0; q < 4; q++)
                    ssum[i][j][q] += __builtin_amdgcn_exp2f(s[i][j][q]) * km4[j][q];
        __syncthreads();
        buf ^= 1;
    }
    #pragma unroll
    for (int i = 0; i < 2; i++)
        #pragma unroll
        for (int j = 0; j < 2; j++) {
            int ng = n0 + wn + i * 16 + frow;
            int mg = m0 + wm + j * 16 + koct * 4;
            *(f32x4*)(partial + (size_t)zg * 1048576 + (size_t)ng * NSEQ + mg) = ssum[i][j];
        }
}

// invS = 1 / (p0+p1+p2+p3)
__launch_bounds__(256)
__global__ void sum_inv(const float* __restrict__ p, float* __restrict__ invS) {
    int i = (blockIdx.x * 256 + threadIdx.x) * 4;
    float4 a = *(const float4*)(p + i);
    float4 b = *(const float4*)(p + 1048576 + i);
    float4 c = *(const float4*)(p + 2097152 + i);
    float4 d = *(const float4*)(p + 3145728 + i);
    float4 r;
    float s;
    s = a.x + b.x + c.x + d.x; r.x = s > 0.f ? 1.f / s : 0.f;
    s = a.y + b.y + c.y + d.y; r.y = s > 0.f ? 1.f / s : 0.f;
    s = a.z + b.z + c.z + d.z; r.z = s > 0.f ? 1.f / s : 0.f;
    s = a.w + b.w + c.w + d.w; r.w = s > 0.f ? 1.f / s : 0.f;
    *(float4*)(invS + i) = r;
}

// ---------------------------------------------------------------------------
// Pass 2: per z, out[z,n,:] = sum_m (exp2(s')*invS) V'[m,:]   (V' = V*km)
// Staged, m-tile 32, lP double-buffered so PV(t-1) runs while scores(t)
// compute (T15); raw barriers + counted vmcnt(2) keep staging in flight (T4).
// grid 1024, XCD c owns z in {8c..8c+7}.
// ---------------------------------------------------------------------------
__launch_bounds__(256)
__global__ void attn_pass2(const u16* __restrict__ Qh, const u16* __restrict__ Kh,
                           const u16* __restrict__ Vt,
                           const float* __restrict__ qm, const float* __restrict__ invS,
                           const u8* __restrict__ pad, float* __restrict__ attn)
{
    __shared__ __align__(16) u16 lK[2][32 * 64];     // [m][d]  4KB each
    __shared__ __align__(16) u16 lV[2][64 * 32];     // [d][m]  4KB each
    __shared__ __align__(16) u16 lP[2][4][16 * 32];  // [pb][wave][n][m] 4KB each
    const int tid = threadIdx.x, lane = tid & 63, w = tid >> 6;
    const int frow = lane & 15, koct = lane >> 4;
    const int bid = blockIdx.x;
    const int z  = (bid & 7) * 8 + ((bid >> 3) & 7);
    const int n0 = (bid >> 6) * 64;
    const int hh = z >> 2, bb = z & 3;
    const int wrow = w * 16;
    const int nl_row = wrow + frow;
    const size_t inv_base = (size_t)(n0 + nl_row) * NSEQ;

    const u16* Kz = Kh + (size_t)z * 65536;
    const u16* Vz = Vt + (size_t)z * 65536;

    // Q fragments (loop-invariant)
    bf16x8 aq[2];
    #pragma unroll
    for (int ks = 0; ks < 2; ks++)
        aq[ks] = *(const bf16x8*)(Qh + (size_t)z * 65536 +
                                  (size_t)(n0 + nl_row) * 64 + ks * 32 + koct * 8);

    // stage one 32-m tile: K 4KB (1 chunk/thread) + V 4KB (1 chunk/thread)
    auto stage = [&](int buf, int m0) {
        {
            int p = tid, row = p >> 3, sl = p & 7, ssl = sl ^ (row & 7);
            gload16(Kz + (size_t)(m0 + row) * 64 + ssl * 8, (char*)lK[buf] + p * 16);
        }
        {
            int p = tid, row = p >> 2, sl = p & 3, ssl = sl ^ (row & 3);
            gload16(Vz + (size_t)row * 1024 + m0 + ssl * 8, (char*)lV[buf] + p * 16);
        }
    };

    f32x4 oacc[4] = {};
    stage(0, 0);
    int buf = 0, pb = 0;

    for (int mt = 0; mt < 32; mt++) {
        // 1. PV of previous tile (lP[pb^1], lV[buf^1]) — off the critical path
        if (mt > 0) {
            const char* lPw = (const char*)&lP[pb ^ 1][w][0];
            bf16x8 pa = *(const bf16x8*)(lPw + frow * 64 + koct * 16);
            __builtin_amdgcn_s_setprio(1);
            #pragma unroll
            for (int dj = 0; dj < 4; dj++) {
                int r = dj * 16 + frow;
                int slot = koct ^ (r & 3);
                bf16x8 vb = *(const bf16x8*)((const char*)lV[buf ^ 1] + r * 64 + slot * 16);
                oacc[dj] = __builtin_amdgcn_mfma_f32_16x16x32_bf16(pa, vb, oacc[dj], 0, 0, 0);
            }
            __builtin_amdgcn_s_setprio(0);
        }
        // 2. all waves done reading lK/lV[buf^1]
        __builtin_amdgcn_s_barrier();
        // 3. stage next tile into buf^1; keep its 2 loads in flight (vmcnt(2))
        if (mt < 31) {
            stage(buf ^ 1, (mt + 1) * 32);
            asm volatile("s_waitcnt vmcnt(2)" ::: "memory");
        } else {
            asm volatile("s_waitcnt vmcnt(0)" ::: "memory");
        }
        __builtin_amdgcn_sched_barrier(0);
        // 4. current tile's staging complete everywhere
        __builtin_amdgcn_s_barrier();
        // 5. scores(t) + P(t) into lP[pb]
        const int m0 = mt * 32;
        f32x4 s[2] = {};
        __builtin_amdgcn_s_setprio(1);
        #pragma unroll
        for (int ks = 0; ks < 2; ks++) {
            #pragma unroll
            for (int j = 0; j < 2; j++) {
                int r = j * 16 + frow;
                int slot = (ks * 4 + koct) ^ (r & 7);
                bf16x8 kb = *(const bf16x8*)((const char*)lK[buf] + r * 128 + slot * 16);
                s[j] = __builtin_amdgcn_mfma_f32_16x16x32_bf16(kb, aq[ks], s[j], 0, 0, 0);
            }
        }
        __builtin_amdgcn_s_setprio(0);
        {
            char* lPw = (char*)&lP[pb][w][0];
            #pragma unroll
            for (int j = 0; j < 2; j++) {
                int mg = m0 + j * 16 + koct * 4;
                f32x4 iv = *(const f32x4*)(invS + inv_base + mg);
                float p0 = __builtin_amdgcn_exp2f(s[j][0]) * iv[0];
                float p1 = __builtin_amdgcn_exp2f(s[j][1]) * iv[1];
                float p2 = __builtin_amdgcn_exp2f(s[j][2]) * iv[2];
                float p3 = __builtin_amdgcn_exp2f(s[j][3]) * iv[3];
                uint2 pk;
                pk.x = cvt_pk_bf16(p0, p1);
                pk.y = cvt_pk_bf16(p2, p3);
                *(uint2*)(lPw + frow * 64 + j * 32 + koct * 8) = pk;
            }
        }
        buf ^= 1; pb ^= 1;
    }
    // final PV for tile 31
    {
        const char* lPw = (const char*)&lP[pb ^ 1][w][0];
        bf16x8 pa = *(const bf16x8*)(lPw + frow * 64 + koct * 16);
        #pragma unroll
        for (int dj = 0; dj < 4; dj++) {
            int r = dj * 16 + frow;
            int slot = koct ^ (r & 3);
            bf16x8 vb = *(const bf16x8*)((const char*)lV[buf ^ 1] + r * 64 + slot * 16);
            oacc[dj] = __builtin_amdgcn_mfma_f32_16x16x32_bf16(pa, vb, oacc[dj], 0, 0, 0);
        }
    }

    #pragma unroll
    for (int q = 0; q < 4; q++) {
        int ns = n0 + wrow + koct * 4 + q;
        float f = qm[z * NSEQ + ns] * (pad[bb * NSEQ + ns] ? 0.f : 1.f);
        #pragma unroll
        for (int dj = 0; dj < 4; dj++) {
            int d = dj * 16 + frow;
            attn[(size_t)(bb * NSEQ + ns) * DMODEL + hh * 64 + d] = oacc[dj][q] * f;
        }
    }
}

// ---------------------------------------------------------------------------
// LayerNorm over last dim (1024), one block per row.
// ---------------------------------------------------------------------------
__launch_bounds__(256)
__global__ void ln_kernel(const float* __restrict__ A, const float* __restrict__ Bv,
                          const float* __restrict__ g, const float* __restrict__ beta,
                          const u8* __restrict__ pad, int mode,
                          float* __restrict__ out, u16* __restrict__ outb)
{
    const int row = blockIdx.x, tid = threadIdx.x;
    const int lane = tid & 63, wv = tid >> 6;
    const float valid = pad[row] ? 0.f : 1.f;
    __shared__ float red[4];

    float4 va = *(const float4*)(A + (size_t)row * 1024 + tid * 4);
    float4 vb = *(const float4*)(Bv + (size_t)row * 1024 + tid * 4);
    float v[4];
    if (mode == 0) {
        v[0] = va.x + vb.x; v[1] = va.y + vb.y; v[2] = va.z + vb.z; v[3] = va.w + vb.w;
    } else {
        v[0] = va.x * valid + vb.x; v[1] = va.y * valid + vb.y;
        v[2] = va.z * valid + vb.z; v[3] = va.w * valid + vb.w;
    }
    float s = v[0] + v[1] + v[2] + v[3];
    #pragma unroll
    for (int off = 32; off > 0; off >>= 1) s += __shfl_down(s, off, 64);
    if (lane == 0) red[wv] = s;
    __syncthreads();
    float mean = (red[0] + red[1] + red[2] + red[3]) * (1.f / 1024.f);
    float sq = 0.f;
    #pragma unroll
    for (int k = 0; k < 4; k++) { float d = v[k] - mean; sq += d * d; }
    __syncthreads();
    #pragma unroll
    for (int off = 32; off > 0; off >>= 1) sq += __shfl_down(sq, off, 64);
    if (lane == 0) red[wv] = sq;
    __syncthreads();
    float var = (red[0] + red[1] + red[2] + red[3]) * (1.f / 1024.f);
    float rstd = rsqrtf(var + 1e-5f);
    float osc = (mode == 0) ? 1.f : valid;
    #pragma unroll
    for (int k = 0; k < 4; k++) {
        int c = tid * 4 + k;
        float o = ((v[k] - mean) * rstd * g[c] + beta[c]) * osc;
        out[(size_t)row * 1024 + c] = o;
        if (outb) outb[(size_t)row * 1024 + c] = f2bf(o);
    }
}

// ---------------------------------------------------------------------------
extern "C" void kernel_launch(void* const* d_in, const int* in_sizes, int n_in,
                              void* d_out, int out_size, void* d_ws, size_t ws_size,
                              hipStream_t stream)
{
    const float* x   = (const float*)d_in[0];
    const u8*    pad = (const u8*)d_in[1];
    const float* Wq  = (const float*)d_in[2];
    const float* Wk  = (const float*)d_in[3];
    const float* Wv  = (const float*)d_in[4];
    const float* W1  = (const float*)d_in[5];
    const float* b1  = (const float*)d_in[6];
    const float* W2  = (const float*)d_in[7];
    const float* b2  = (const float*)d_in[8];
    const float* g1  = (const float*)d_in[9];
    const float* be1 = (const float*)d_in[10];
    const float* g2  = (const float*)d_in[11];
    const float* be2 = (const float*)d_in[12];
    float* out = (float*)d_out;

    // workspace (~99 MB)
    u16* xb   = (u16*)d_ws;
    u16* Wqb  = xb   + 4194304;
    u16* Wkb  = Wqb  + 1048576;
    u16* Wvb  = Wkb  + 1048576;
    u16* W1b  = Wvb  + 1048576;
    u16* W2b  = W1b  + 1048576;
    u16* Qh   = W2b  + 1048576;        // [z][n][dh]
    u16* Kh   = Qh   + 4194304;        // [z][n][dh]
    u16* Vt   = Kh   + 4194304;        // [z][dh][n]  (km applied by vt_km)
    u16* hb   = Vt   + 4194304;
    u16* ff1b = hb   + 4194304;
    float* km      = (float*)(ff1b + 4194304);
    float* qm      = km      + 65536;
    float* partial = qm      + 65536;           // 4M f32
    float* invS    = partial + 4194304;         // 1M f32
    float* h       = invS    + 1048576;         // 4M f32

    cvt_bf16<<<4096, 256, 0, stream>>>(x, xb);
    P5 p5;
    p5.in[0] = Wq; p5.in[1] = Wk; p5.in[2] = Wv; p5.in[3] = W1; p5.in[4] = W2;
    p5.out[0] = Wqb; p5.out[1] = Wkb; p5.out[2] = Wvb; p5.out[3] = W1b; p5.out[4] = W2b;
    cvt_bf16_5<<<5120, 256, 0, stream>>>(p5);

    // fused Q/K/V projections, m97-structure 128x128 tiles
    gemm_qkv<<<dim3(24, 32), 256, 0, stream>>>(xb, Wqb, Wkb, Wvb, Qh, Kh, Vt);

    rowmask2_bf<<<512, 256, 0, stream>>>(Kh, Qh, km, qm);
    vt_km<<<4096, 256, 0, stream>>>(Vt, km);

    attn_pass1<<<1024, 256, 0, stream>>>(Qh, Kh, km, partial);
    sum_inv<<<1024, 256, 0, stream>>>(partial, invS);
    attn_pass2<<<1024, 256, 0, stream>>>(Qh, Kh, Vt, qm, invS, pad, out);

    ln_kernel<<<4096, 256, 0, stream>>>(x, out, g1, be1, pad, 0, h, hb);

    gemm_bt<2><<<dim3(16, 32), 256, 0, stream>>>(hb,   W1b, b1, ff1b);
    gemm_bt<3><<<dim3(16, 32), 256, 0, stream>>>(ff1b, W2b, b2, out);

    ln_kernel<<<4096, 256, 0, stream>>>(out, h, g2, be2, pad, 1, out, nullptr);
}

// Round 10
// 202.365 us; speedup vs baseline: 1.3921x; 1.0024x over previous
//
#include <hip/hip_runtime.h>
#include <math.h>

typedef unsigned short u16;
typedef unsigned char  u8;
typedef unsigned int   u32;
typedef __attribute__((ext_vector_type(8))) short bf16x8;
typedef __attribute__((ext_vector_type(4))) float f32x4;

#define NSEQ   1024
#define DMODEL 1024
#define ZTOT   64
#define LOG2E  1.4426950408889634f

typedef const __attribute__((address_space(1))) void* gp1;
typedef __attribute__((address_space(3))) void* lp3;

__device__ __forceinline__ void gload16(const void* g, void* l) {
    __builtin_amdgcn_global_load_lds((gp1)g, (lp3)l, 16, 0, 0);
}

__device__ __forceinline__ u16 f2bf(float f) {
    u32 u = __builtin_bit_cast(u32, f);
    return (u16)((u + 0x7FFFu + ((u >> 16) & 1u)) >> 16);
}

// HW packed f32->bf16 (RNE), 2 values -> 1 dword
__device__ __forceinline__ u32 cvt_pk_bf16(float a, float b) {
    u32 r;
    asm("v_cvt_pk_bf16_f32 %0, %1, %2" : "=v"(r) : "v"(a), "v"(b));
    return r;
}

// ---------------------------------------------------------------------------
// fp32 -> bf16 elementwise: x (4M elems, blocks 0..4095) + 5 weights
// (1M each, blocks 4096..9215) in ONE launch.
// ---------------------------------------------------------------------------
struct P5 { const float* in[5]; u16* out[5]; };
__launch_bounds__(256)
__global__ void cvt_all(const float* __restrict__ x, u16* __restrict__ xb, P5 p) {
    int bid = blockIdx.x;
    const float* in;
    u16* out;
    int blk;
    if (bid < 4096) { in = x; out = xb; blk = bid; }
    else {
        int which = (bid - 4096) >> 10;
        blk = bid & 1023;
        in = p.in[which];
        out = p.out[which];
    }
    int i = (blk * 256 + threadIdx.x) * 4;
    float4 v = *(const float4*)(in + i);
    uint2 o;
    o.x = cvt_pk_bf16(v.x, v.y);
    o.y = cvt_pk_bf16(v.z, v.w);
    *(uint2*)(out + i) = o;
}

// sign(sum |row|) over 64 bf16 -> 0/1 ; grid 512: first half Kh->km, second Qh->qm
__launch_bounds__(256)
__global__ void rowmask2_bf(const u16* __restrict__ Kh, const u16* __restrict__ Qh,
                            float* __restrict__ km, float* __restrict__ qm) {
    int b = blockIdx.x;
    const u16* T = (b < 256) ? Kh : Qh;
    float* o = (b < 256) ? km : qm;
    int r = (b & 255) * 256 + threadIdx.x;
    const uint4* p = (const uint4*)(T + (size_t)r * 64);
    u32 acc = 0;
    #pragma unroll
    for (int i = 0; i < 8; i++) {
        uint4 q = p[i];
        acc |= (q.x | q.y | q.z | q.w) & 0x7fff7fffu;
    }
    o[r] = acc ? 1.f : 0.f;
}

// Vt[z][dh][tok] &= (km[z][tok] != 0)
__launch_bounds__(256)
__global__ void vt_km(u16* __restrict__ Vt, const float* __restrict__ km) {
    int idx = blockIdx.x * 256 + threadIdx.x;  // uint4 index (8 bf16)
    int e0 = idx * 8;
    int z = e0 >> 16;
    int tok = e0 & 1023;
    float4 ka = *(const float4*)(km + z * 1024 + tok);
    float4 kb = *(const float4*)(km + z * 1024 + tok + 4);
    uint4 v = *(uint4*)(Vt + e0);
    u32 m;
    m = (ka.x != 0.f ? 0x0000FFFFu : 0u) | (ka.y != 0.f ? 0xFFFF0000u : 0u); v.x &= m;
    m = (ka.z != 0.f ? 0x0000FFFFu : 0u) | (ka.w != 0.f ? 0xFFFF0000u : 0u); v.y &= m;
    m = (kb.x != 0.f ? 0x0000FFFFu : 0u) | (kb.y != 0.f ? 0xFFFF0000u : 0u); v.z &= m;
    m = (kb.z != 0.f ? 0x0000FFFFu : 0u) | (kb.w != 0.f ? 0xFFFF0000u : 0u); v.w &= m;
    *(uint4*)(Vt + e0) = v;
}

// ---------------------------------------------------------------------------
// Fused QKV projection GEMM, m97 structure: BM=BN=128, BK=32, 4 waves.
// grid (24, 32): bx>>3 selects {Q, K, V}.
// ---------------------------------------------------------------------------
__launch_bounds__(256)
__global__ void gemm_qkv(const u16* __restrict__ A,
                         const u16* __restrict__ Wq, const u16* __restrict__ Wk,
                         const u16* __restrict__ Wv,
                         u16* __restrict__ Qh, u16* __restrict__ Kh, u16* __restrict__ Vt)
{
    __shared__ __align__(16) u16 lA[2][128 * 32];
    __shared__ __align__(16) u16 lB[2][128 * 32];
    const int tid = threadIdx.x, lane = tid & 63, w = tid >> 6;
    const int frow = lane & 15, koct = lane >> 4;
    const int sel = blockIdx.x >> 3;
    const int col0 = (blockIdx.x & 7) * 128, row0 = blockIdx.y * 128;
    const u16* B = (sel == 0) ? Wq : (sel == 1) ? Wk : Wv;
    const int wrow = (w >> 1) * 64, wcol = (w & 1) * 64;
    f32x4 acc[4][4] = {};

    auto stage = [&](int buf, int k0) {
        #pragma unroll
        for (int i = 0; i < 2; i++) {
            int p = tid + i * 256;
            int row = p >> 2, sl = p & 3, ssl = sl ^ ((row >> 1) & 3);
            gload16(A + (size_t)(row0 + row) * 1024 + k0 + ssl * 8, (char*)lA[buf] + p * 16);
        }
        #pragma unroll
        for (int i = 0; i < 2; i++) {
            int p = tid + i * 256;
            int row = p >> 2, sl = p & 3, ssl = sl ^ ((row >> 1) & 3);
            gload16(B + (size_t)(col0 + row) * 1024 + k0 + ssl * 8, (char*)lB[buf] + p * 16);
        }
    };

    stage(0, 0);
    __syncthreads();
    int buf = 0;
    for (int k0 = 0; k0 < 1024; k0 += 32) {
        if (k0 + 32 < 1024) stage(buf ^ 1, k0 + 32);
        __builtin_amdgcn_s_setprio(1);
        bf16x8 af[4], bf[4];
        #pragma unroll
        for (int i = 0; i < 4; i++) {
            int r = wrow + i * 16 + frow;
            int sl = koct ^ ((r >> 1) & 3);
            af[i] = *(const bf16x8*)((const char*)lA[buf] + r * 64 + sl * 16);
        }
        #pragma unroll
        for (int j = 0; j < 4; j++) {
            int r = wcol + j * 16 + frow;
            int sl = koct ^ ((r >> 1) & 3);
            bf[j] = *(const bf16x8*)((const char*)lB[buf] + r * 64 + sl * 16);
        }
        #pragma unroll
        for (int i = 0; i < 4; i++)
            #pragma unroll
            for (int j = 0; j < 4; j++)
                acc[i][j] = __builtin_amdgcn_mfma_f32_16x16x32_bf16(af[i], bf[j], acc[i][j], 0, 0, 0);
        __builtin_amdgcn_s_setprio(0);
        __syncthreads();
        buf ^= 1;
    }

    if (sel < 2) {
        const float scale = (sel == 0) ? 0.125f * LOG2E : 1.0f;
        u16* outp = (sel == 0) ? Qh : Kh;
        #pragma unroll
        for (int i = 0; i < 4; i++)
            #pragma unroll
            for (int j = 0; j < 4; j++)
                #pragma unroll
                for (int q = 0; q < 4; q++) {
                    int r = row0 + wrow + i * 16 + koct * 4 + q;
                    int c = col0 + wcol + j * 16 + frow;
                    float v = acc[i][j][q] * scale;
                    outp[(size_t)((c >> 6) * 4 + (r >> 10)) * 65536 +
                         (size_t)(r & 1023) * 64 + (c & 63)] = f2bf(v);
                }
    } else {
        #pragma unroll
        for (int i = 0; i < 4; i++) {
            int r0 = row0 + wrow + i * 16 + koct * 4;   // token base (mult of 4)
            #pragma unroll
            for (int j = 0; j < 4; j++) {
                int c = col0 + wcol + j * 16 + frow;    // channel
                int z = (c >> 6) * 4 + (r0 >> 10);
                uint2 pk;
                pk.x = cvt_pk_bf16(acc[i][j][0], acc[i][j][1]);
                pk.y = cvt_pk_bf16(acc[i][j][2], acc[i][j][3]);
                *(uint2*)(Vt + (size_t)z * 65536 + (size_t)(c & 63) * 1024 + (r0 & 1023)) = pk;
            }
        }
    }
}

// ---------------------------------------------------------------------------
// bf16 MFMA GEMM for FFN. MODE 2: +bias+relu bf16. MODE 3: +bias f32.
// ---------------------------------------------------------------------------
template <int MODE>
__launch_bounds__(256)
__global__ void gemm_bt(const u16* __restrict__ A, const u16* __restrict__ B,
                        const float* __restrict__ bias, void* __restrict__ outp)
{
    __shared__ __align__(16) u16 lA[2][128 * 64];
    __shared__ __align__(16) u16 lB[2][64 * 64];
    const int tid = threadIdx.x, lane = tid & 63, w = tid >> 6;
    const int frow = lane & 15, koct = lane >> 4;
    const int col0 = blockIdx.x * 64, row0 = blockIdx.y * 128;
    const int wrow = (w >> 1) * 64, wcol = (w & 1) * 32;
    f32x4 acc[4][2] = {};

    auto stage = [&](int buf, int k0) {
        #pragma unroll
        for (int i = 0; i < 4; i++) {
            int p = tid + i * 256;
            int row = p >> 3, sl = p & 7, ssl = sl ^ (row & 7);
            gload16(A + (size_t)(row0 + row) * 1024 + k0 + ssl * 8, (char*)lA[buf] + p * 16);
        }
        #pragma unroll
        for (int i = 0; i < 2; i++) {
            int p = tid + i * 256;
            int row = p >> 3, sl = p & 7, ssl = sl ^ (row & 7);
            gload16(B + (size_t)(col0 + row) * 1024 + k0 + ssl * 8, (char*)lB[buf] + p * 16);
        }
    };

    stage(0, 0);
    __syncthreads();
    int buf = 0;
    for (int k0 = 0; k0 < 1024; k0 += 64) {
        if (k0 + 64 < 1024) stage(buf ^ 1, k0 + 64);
        __builtin_amdgcn_s_setprio(1);
        #pragma unroll
        for (int ks = 0; ks < 2; ks++) {
            bf16x8 af[4], bf2[2];
            #pragma unroll
            for (int i = 0; i < 4; i++) {
                int r = wrow + i * 16 + frow;
                int sl = (ks * 4 + koct) ^ (r & 7);
                af[i] = *(const bf16x8*)((const char*)lA[buf] + r * 128 + sl * 16);
            }
            #pragma unroll
            for (int j = 0; j < 2; j++) {
                int r = wcol + j * 16 + frow;
                int sl = (ks * 4 + koct) ^ (r & 7);
                bf2[j] = *(const bf16x8*)((const char*)lB[buf] + r * 128 + sl * 16);
            }
            #pragma unroll
            for (int i = 0; i < 4; i++)
                #pragma unroll
                for (int j = 0; j < 2; j++)
                    acc[i][j] = __builtin_amdgcn_mfma_f32_16x16x32_bf16(af[i], bf2[j], acc[i][j], 0, 0, 0);
        }
        __builtin_amdgcn_s_setprio(0);
        __syncthreads();
        buf ^= 1;
    }

    #pragma unroll
    for (int i = 0; i < 4; i++)
        #pragma unroll
        for (int j = 0; j < 2; j++)
            #pragma unroll
            for (int q = 0; q < 4; q++) {
                int r = row0 + wrow + i * 16 + koct * 4 + q;
                int c = col0 + wcol + j * 16 + frow;
                float v = acc[i][j][q] + bias[c];
                if constexpr (MODE == 2) {
                    v = fmaxf(v, 0.f);
                    ((u16*)outp)[(size_t)r * 1024 + c] = f2bf(v);
                } else {
                    ((float*)outp)[(size_t)r * 1024 + c] = v;
                }
            }
}

// ---------------------------------------------------------------------------
// Pass 1: partial[zg][n][m] = sum_{z in zg*16..+16} exp2(s'_znm) * km01(z,m)
// 1-D grid 1024, XCD-swizzled: XCD c owns one zg x 8 m-tiles.
// ---------------------------------------------------------------------------
__launch_bounds__(256)
__global__ void attn_pass1(const u16* __restrict__ Qh, const u16* __restrict__ Kh,
                           const float* __restrict__ km, float* __restrict__ partial)
{
    const int bid = blockIdx.x;
    const int mtzg = (bid & 7) * 8 + ((bid >> 3) & 7);   // cluster per XCD
    const int m0 = (mtzg & 15) * 64, zg = mtzg >> 4;
    const int n0 = (bid >> 6) * 64;

    __shared__ __align__(16) u16 lQ[2][64 * 64];
    __shared__ __align__(16) u16 lK[2][64 * 64];
    const int tid = threadIdx.x, lane = tid & 63, w = tid >> 6;
    const int frow = lane & 15, koct = lane >> 4;
    const int wn = (w >> 1) * 32, wm = (w & 1) * 32;
    f32x4 ssum[2][2] = {};

    auto stage = [&](int buf, int z) {
        #pragma unroll
        for (int i = 0; i < 2; i++) {
            int p = tid + i * 256;
            int row = p >> 3, sl = p & 7, ssl = sl ^ (row & 7);
            gload16(Qh + (size_t)(z * NSEQ + n0 + row) * 64 + ssl * 8, (char*)lQ[buf] + p * 16);
            gload16(Kh + (size_t)(z * NSEQ + m0 + row) * 64 + ssl * 8, (char*)lK[buf] + p * 16);
        }
    };

    const int z0 = zg * 16;
    stage(0, z0);
    __syncthreads();
    int buf = 0;
    for (int zi = 0; zi < 16; zi++) {
        const int z = z0 + zi;
        if (zi < 15) stage(buf ^ 1, z + 1);
        f32x4 km4[2];
        #pragma unroll
        for (int j = 0; j < 2; j++)
            km4[j] = *(const f32x4*)(km + z * NSEQ + m0 + wm + j * 16 + koct * 4);
        f32x4 s[2][2] = {};
        __builtin_amdgcn_s_setprio(1);
        #pragma unroll
        for (int ks = 0; ks < 2; ks++) {
            bf16x8 a[2], b2[2];
            #pragma unroll
            for (int i = 0; i < 2; i++) {
                int r = wn + i * 16 + frow;
                int sl = (ks * 4 + koct) ^ (r & 7);
                a[i] = *(const bf16x8*)((const char*)lQ[buf] + r * 128 + sl * 16);
            }
            #pragma unroll
            for (int j = 0; j < 2; j++) {
                int r = wm + j * 16 + frow;
                int sl = (ks * 4 + koct) ^ (r & 7);
                b2[j] = *(const bf16x8*)((const char*)lK[buf] + r * 128 + sl * 16);
            }
            #pragma unroll
            for (int i = 0; i < 2; i++)
                #pragma unroll
                for (int j = 0; j < 2; j++)
                    s[i][j] = __builtin_amdgcn_mfma_f32_16x16x32_bf16(b2[j], a[i], s[i][j], 0, 0, 0);
        }
        __builtin_amdgcn_s_setprio(0);
        #pragma unroll
        for (int j = 0; j < 2; j++)
            #pragma unroll
            for (int i = 0; i < 2; i++)
                #pragma unroll
                for (int q = 0; q < 4; q++)
                    ssum[i][j][q] += __builtin_amdgcn_exp2f(s[i][j][q]) * km4[j][q];
        __syncthreads();
        buf ^= 1;
    }
    #pragma unroll
    for (int i = 0; i < 2; i++)
        #pragma unroll
        for (int j = 0; j < 2; j++) {
            int ng = n0 + wn + i * 16 + frow;
            int mg = m0 + wm + j * 16 + koct * 4;
            *(f32x4*)(partial + (size_t)zg * 1048576 + (size_t)ng * NSEQ + mg) = ssum[i][j];
        }
}

// invS = 1 / (p0+p1+p2+p3)
__launch_bounds__(256)
__global__ void sum_inv(const float* __restrict__ p, float* __restrict__ invS) {
    int i = (blockIdx.x * 256 + threadIdx.x) * 4;
    float4 a = *(const float4*)(p + i);
    float4 b = *(const float4*)(p + 1048576 + i);
    float4 c = *(const float4*)(p + 2097152 + i);
    float4 d = *(const float4*)(p + 3145728 + i);
    float4 r;
    float s;
    s = a.x + b.x + c.x + d.x; r.x = s > 0.f ? 1.f / s : 0.f;
    s = a.y + b.y + c.y + d.y; r.y = s > 0.f ? 1.f / s : 0.f;
    s = a.z + b.z + c.z + d.z; r.z = s > 0.f ? 1.f / s : 0.f;
    s = a.w + b.w + c.w + d.w; r.w = s > 0.f ? 1.f / s : 0.f;
    *(float4*)(invS + i) = r;
}

// ---------------------------------------------------------------------------
// Pass 2: per z, out[z,n,:] = sum_m (exp2(s')*invS) V'[m,:]   (V' = V*km)
// m-tile = 128, 8 iterations, SINGLE-buffered K/V (fewer sync/drain events),
// each tile processed as two 64-m sub-phases sharing one staging.
// LDS: lK 16KB + lV 16KB + lP 8KB = 40KB -> 4 blocks/CU.
// grid 1024, XCD c owns z in {8c..8c+7}.
// ---------------------------------------------------------------------------
__launch_bounds__(256)
__global__ void attn_pass2(const u16* __restrict__ Qh, const u16* __restrict__ Kh,
                           const u16* __restrict__ Vt,
                           const float* __restrict__ qm, const float* __restrict__ invS,
                           const u8* __restrict__ pad, float* __restrict__ attn)
{
    __shared__ __align__(16) u16 lK[128 * 64];       // [m][d] rows 128B
    __shared__ __align__(16) u16 lV[64 * 128];       // [d][m] rows 256B
    __shared__ __align__(16) u16 lP[4][16 * 64];     // per-wave [n][m-half] rows 128B
    const int tid = threadIdx.x, lane = tid & 63, w = tid >> 6;
    const int frow = lane & 15, koct = lane >> 4;
    const int bid = blockIdx.x;
    const int z  = (bid & 7) * 8 + ((bid >> 3) & 7);
    const int n0 = (bid >> 6) * 64;
    const int hh = z >> 2, bb = z & 3;
    const int wrow = w * 16;
    const size_t inv_base = (size_t)(n0 + wrow + frow) * NSEQ;
    char* lPw = (char*)&lP[w][0];

    const u16* Kz = Kh + (size_t)z * 65536;
    const u16* Vz = Vt + (size_t)z * 65536;

    // Q fragments (loop-invariant)
    bf16x8 aq[2];
    #pragma unroll
    for (int ks = 0; ks < 2; ks++)
        aq[ks] = *(const bf16x8*)(Qh + (size_t)z * 65536 +
                                  (size_t)(n0 + wrow + frow) * 64 + ks * 32 + koct * 8);

    // stage one 128-m tile: K 16KB (4 chunks/thread) + V 16KB (4 chunks/thread)
    auto stage = [&](int m0) {
        #pragma unroll
        for (int i = 0; i < 4; i++) {
            int p = tid + i * 256;
            int row = p >> 3, sl = p & 7, ssl = sl ^ (row & 7);
            gload16(Kz + (size_t)(m0 + row) * 64 + ssl * 8, (char*)lK + p * 16);
        }
        #pragma unroll
        for (int i = 0; i < 4; i++) {
            int p = tid + i * 256;
            int row = p >> 4, sl = p & 15, ssl = sl ^ (row & 15);
            gload16(Vz + (size_t)row * 1024 + m0 + ssl * 8, (char*)lV + p * 16);
        }
    };

    f32x4 oacc[4] = {};
    f32x4 ivA[4], ivB[4];
    #pragma unroll
    for (int j = 0; j < 4; j++)
        ivA[j] = *(const f32x4*)(invS + inv_base + j * 16 + koct * 4);
    stage(0);
    asm volatile("s_waitcnt vmcnt(0)" ::: "memory");
    __builtin_amdgcn_sched_barrier(0);
    __builtin_amdgcn_s_barrier();

    for (int mt = 0; mt < 8; mt++) {
        const int m0 = mt * 128;
        // prefetch invS for half B
        #pragma unroll
        for (int j = 0; j < 4; j++)
            ivB[j] = *(const f32x4*)(invS + inv_base + m0 + 64 + j * 16 + koct * 4);

        #pragma unroll
        for (int half = 0; half < 2; half++) {
            // scores for this 64-m half
            f32x4 s[4] = {};
            __builtin_amdgcn_s_setprio(1);
            #pragma unroll
            for (int ks = 0; ks < 2; ks++) {
                bf16x8 kb[4];
                #pragma unroll
                for (int j = 0; j < 4; j++) {
                    int r = half * 64 + j * 16 + frow;
                    int sl = (ks * 4 + koct) ^ (r & 7);
                    kb[j] = *(const bf16x8*)((const char*)lK + r * 128 + sl * 16);
                }
                #pragma unroll
                for (int j = 0; j < 4; j++)
                    s[j] = __builtin_amdgcn_mfma_f32_16x16x32_bf16(kb[j], aq[ks], s[j], 0, 0, 0);
            }
            __builtin_amdgcn_s_setprio(0);
            // prefetch next tile's half-A invS during half B
            if (half == 1 && mt < 7) {
                #pragma unroll
                for (int j = 0; j < 4; j++)
                    ivA[j] = *(const f32x4*)(invS + inv_base + m0 + 128 + j * 16 + koct * 4);
            }
            // P = exp2(s)*invS -> bf16 pairs -> wave-private lP
            #pragma unroll
            for (int j = 0; j < 4; j++) {
                f32x4 iv = half ? ivB[j] : ivA[j];
                float p0 = __builtin_amdgcn_exp2f(s[j][0]) * iv[0];
                float p1 = __builtin_amdgcn_exp2f(s[j][1]) * iv[1];
                float p2 = __builtin_amdgcn_exp2f(s[j][2]) * iv[2];
                float p3 = __builtin_amdgcn_exp2f(s[j][3]) * iv[3];
                uint2 pk;
                pk.x = cvt_pk_bf16(p0, p1);
                pk.y = cvt_pk_bf16(p2, p3);
                int slot = (j * 2 + (koct >> 1)) ^ (frow & 7);
                *(uint2*)(lPw + frow * 128 + slot * 16 + (koct & 1) * 8) = pk;
            }
            // PV for this half
            __builtin_amdgcn_s_setprio(1);
            #pragma unroll
            for (int ks = 0; ks < 2; ks++) {
                int slp = (ks * 4 + koct) ^ (frow & 7);
                bf16x8 pa = *(const bf16x8*)(lPw + frow * 128 + slp * 16);
                #pragma unroll
                for (int dj = 0; dj < 4; dj++) {
                    int r = dj * 16 + frow;
                    int s0 = half * 8 + ks * 4 + koct;
                    int sv = s0 ^ (r & 15);
                    bf16x8 vb = *(const bf16x8*)((const char*)lV + r * 256 + sv * 16);
                    oacc[dj] = __builtin_amdgcn_mfma_f32_16x16x32_bf16(pa, vb, oacc[dj], 0, 0, 0);
                }
            }
            __builtin_amdgcn_s_setprio(0);
        }
        // all waves done reading this tile, then restage
        __builtin_amdgcn_s_barrier();
        if (mt < 7) stage(m0 + 128);
        asm volatile("s_waitcnt vmcnt(0)" ::: "memory");
        __builtin_amdgcn_sched_barrier(0);
        __builtin_amdgcn_s_barrier();
    }

    #pragma unroll
    for (int q = 0; q < 4; q++) {
        int ns = n0 + wrow + koct * 4 + q;
        float f = qm[z * NSEQ + ns] * (pad[bb * NSEQ + ns] ? 0.f : 1.f);
        #pragma unroll
        for (int dj = 0; dj < 4; dj++) {
            int d = dj * 16 + frow;
            attn[(size_t)(bb * NSEQ + ns) * DMODEL + hh * 64 + d] = oacc[dj][q] * f;
        }
    }
}

// ---------------------------------------------------------------------------
// LayerNorm over last dim (1024), one block per row.
// ---------------------------------------------------------------------------
__launch_bounds__(256)
__global__ void ln_kernel(const float* __restrict__ A, const float* __restrict__ Bv,
                          const float* __restrict__ g, const float* __restrict__ beta,
                          const u8* __restrict__ pad, int mode,
                          float* __restrict__ out, u16* __restrict__ outb)
{
    const int row = blockIdx.x, tid = threadIdx.x;
    const int lane = tid & 63, wv = tid >> 6;
    const float valid = pad[row] ? 0.f : 1.f;
    __shared__ float red[4];

    float4 va = *(const float4*)(A + (size_t)row * 1024 + tid * 4);
    float4 vb = *(const float4*)(Bv + (size_t)row * 1024 + tid * 4);
    float v[4];
    if (mode == 0) {
        v[0] = va.x + vb.x; v[1] = va.y + vb.y; v[2] = va.z + vb.z; v[3] = va.w + vb.w;
    } else {
        v[0] = va.x * valid + vb.x; v[1] = va.y * valid + vb.y;
        v[2] = va.z * valid + vb.z; v[3] = va.w * valid + vb.w;
    }
    float s = v[0] + v[1] + v[2] + v[3];
    #pragma unroll
    for (int off = 32; off > 0; off >>= 1) s += __shfl_down(s, off, 64);
    if (lane == 0) red[wv] = s;
    __syncthreads();
    float mean = (red[0] + red[1] + red[2] + red[3]) * (1.f / 1024.f);
    float sq = 0.f;
    #pragma unroll
    for (int k = 0; k < 4; k++) { float d = v[k] - mean; sq += d * d; }
    __syncthreads();
    #pragma unroll
    for (int off = 32; off > 0; off >>= 1) sq += __shfl_down(sq, off, 64);
    if (lane == 0) red[wv] = sq;
    __syncthreads();
    float var = (red[0] + red[1] + red[2] + red[3]) * (1.f / 1024.f);
    float rstd = rsqrtf(var + 1e-5f);
    float osc = (mode == 0) ? 1.f : valid;
    #pragma unroll
    for (int k = 0; k < 4; k++) {
        int c = tid * 4 + k;
        float o = ((v[k] - mean) * rstd * g[c] + beta[c]) * osc;
        out[(size_t)row * 1024 + c] = o;
        if (outb) outb[(size_t)row * 1024 + c] = f2bf(o);
    }
}

// ---------------------------------------------------------------------------
extern "C" void kernel_launch(void* const* d_in, const int* in_sizes, int n_in,
                              void* d_out, int out_size, void* d_ws, size_t ws_size,
                              hipStream_t stream)
{
    const float* x   = (const float*)d_in[0];
    const u8*    pad = (const u8*)d_in[1];
    const float* Wq  = (const float*)d_in[2];
    const float* Wk  = (const float*)d_in[3];
    const float* Wv  = (const float*)d_in[4];
    const float* W1  = (const float*)d_in[5];
    const float* b1  = (const float*)d_in[6];
    const float* W2  = (const float*)d_in[7];
    const float* b2  = (const float*)d_in[8];
    const float* g1  = (const float*)d_in[9];
    const float* be1 = (const float*)d_in[10];
    const float* g2  = (const float*)d_in[11];
    const float* be2 = (const float*)d_in[12];
    float* out = (float*)d_out;

    // workspace (~95 MB)
    u16* xb   = (u16*)d_ws;
    u16* Wqb  = xb   + 4194304;
    u16* Wkb  = Wqb  + 1048576;
    u16* Wvb  = Wkb  + 1048576;
    u16* W1b  = Wvb  + 1048576;
    u16* W2b  = W1b  + 1048576;
    u16* Qh   = W2b  + 1048576;        // [z][n][dh]
    u16* Kh   = Qh   + 4194304;        // [z][n][dh]
    u16* Vt   = Kh   + 4194304;        // [z][dh][n]  (km applied by vt_km)
    u16* hb   = Vt   + 4194304;
    u16* ff1b = hb   + 4194304;
    float* km      = (float*)(ff1b + 4194304);
    float* qm      = km      + 65536;
    float* partial = qm      + 65536;           // 4M f32
    float* invS    = partial + 4194304;         // 1M f32
    float* h       = invS    + 1048576;         // 4M f32

    P5 p5;
    p5.in[0] = Wq; p5.in[1] = Wk; p5.in[2] = Wv; p5.in[3] = W1; p5.in[4] = W2;
    p5.out[0] = Wqb; p5.out[1] = Wkb; p5.out[2] = Wvb; p5.out[3] = W1b; p5.out[4] = W2b;
    cvt_all<<<9216, 256, 0, stream>>>(x, xb, p5);

    // fused Q/K/V projections, m97-structure 128x128 tiles
    gemm_qkv<<<dim3(24, 32), 256, 0, stream>>>(xb, Wqb, Wkb, Wvb, Qh, Kh, Vt);

    rowmask2_bf<<<512, 256, 0, stream>>>(Kh, Qh, km, qm);
    vt_km<<<4096, 256, 0, stream>>>(Vt, km);

    attn_pass1<<<1024, 256, 0, stream>>>(Qh, Kh, km, partial);
    sum_inv<<<1024, 256, 0, stream>>>(partial, invS);
    attn_pass2<<<1024, 256, 0, stream>>>(Qh, Kh, Vt, qm, invS, pad, out);

    ln_kernel<<<4096, 256, 0, stream>>>(x, out, g1, be1, pad, 0, h, hb);

    gemm_bt<2><<<dim3(16, 32), 256, 0, stream>>>(hb,   W1b, b1, ff1b);
    gemm_bt<3><<<dim3(16, 32), 256, 0, stream>>>(ff1b, W2b, b2, out);

    ln_kernel<<<4096, 256, 0, stream>>>(out, h, g2, be2, pad, 1, out, nullptr);
}

// Round 11
// 177.151 us; speedup vs baseline: 1.5903x; 1.1423x over previous
//
#include <hip/hip_runtime.h>
#include <math.h>

typedef unsigned short u16;
typedef unsigned char  u8;
typedef unsigned int   u32;
typedef __attribute__((ext_vector_type(8))) short bf16x8;
typedef __attribute__((ext_vector_type(4))) float f32x4;

#define NSEQ   1024
#define DMODEL 1024
#define ZTOT   64
#define LOG2E  1.4426950408889634f

typedef const __attribute__((address_space(1))) void* gp1;
typedef __attribute__((address_space(3))) void* lp3;

__device__ __forceinline__ void gload16(const void* g, void* l) {
    __builtin_amdgcn_global_load_lds((gp1)g, (lp3)l, 16, 0, 0);
}

__device__ __forceinline__ u16 f2bf(float f) {
    u32 u = __builtin_bit_cast(u32, f);
    return (u16)((u + 0x7FFFu + ((u >> 16) & 1u)) >> 16);
}

__device__ __forceinline__ float bf2f(u32 lo16) {
    u32 t = lo16 << 16;
    return __builtin_bit_cast(float, t);
}

// HW packed f32->bf16 (RNE), 2 values -> 1 dword
__device__ __forceinline__ u32 cvt_pk_bf16(float a, float b) {
    u32 r;
    asm("v_cvt_pk_bf16_f32 %0, %1, %2" : "=v"(r) : "v"(a), "v"(b));
    return r;
}

// ---------------------------------------------------------------------------
// fp32 -> bf16 elementwise: x (4M elems) + 5 weights (1M each) in ONE launch.
// ---------------------------------------------------------------------------
struct P5 { const float* in[5]; u16* out[5]; };
__launch_bounds__(256)
__global__ void cvt_all(const float* __restrict__ x, u16* __restrict__ xb, P5 p) {
    int bid = blockIdx.x;
    const float* in;
    u16* out;
    int blk;
    if (bid < 4096) { in = x; out = xb; blk = bid; }
    else {
        int which = (bid - 4096) >> 10;
        blk = bid & 1023;
        in = p.in[which];
        out = p.out[which];
    }
    int i = (blk * 256 + threadIdx.x) * 4;
    float4 v = *(const float4*)(in + i);
    uint2 o;
    o.x = cvt_pk_bf16(v.x, v.y);
    o.y = cvt_pk_bf16(v.z, v.w);
    *(uint2*)(out + i) = o;
}

// sign(sum |row|) over 64 bf16 -> 0/1 ; grid 512: first half Kh->km, second Qh->qm
__launch_bounds__(256)
__global__ void rowmask2_bf(const u16* __restrict__ Kh, const u16* __restrict__ Qh,
                            float* __restrict__ km, float* __restrict__ qm) {
    int b = blockIdx.x;
    const u16* T = (b < 256) ? Kh : Qh;
    float* o = (b < 256) ? km : qm;
    int r = (b & 255) * 256 + threadIdx.x;
    const uint4* p = (const uint4*)(T + (size_t)r * 64);
    u32 acc = 0;
    #pragma unroll
    for (int i = 0; i < 8; i++) {
        uint4 q = p[i];
        acc |= (q.x | q.y | q.z | q.w) & 0x7fff7fffu;
    }
    o[r] = acc ? 1.f : 0.f;
}

// Vt[z][dh][tok] &= (km[z][tok] != 0)
__launch_bounds__(256)
__global__ void vt_km(u16* __restrict__ Vt, const float* __restrict__ km) {
    int idx = blockIdx.x * 256 + threadIdx.x;  // uint4 index (8 bf16)
    int e0 = idx * 8;
    int z = e0 >> 16;
    int tok = e0 & 1023;
    float4 ka = *(const float4*)(km + z * 1024 + tok);
    float4 kb = *(const float4*)(km + z * 1024 + tok + 4);
    uint4 v = *(uint4*)(Vt + e0);
    u32 m;
    m = (ka.x != 0.f ? 0x0000FFFFu : 0u) | (ka.y != 0.f ? 0xFFFF0000u : 0u); v.x &= m;
    m = (ka.z != 0.f ? 0x0000FFFFu : 0u) | (ka.w != 0.f ? 0xFFFF0000u : 0u); v.y &= m;
    m = (kb.x != 0.f ? 0x0000FFFFu : 0u) | (kb.y != 0.f ? 0xFFFF0000u : 0u); v.z &= m;
    m = (kb.z != 0.f ? 0x0000FFFFu : 0u) | (kb.w != 0.f ? 0xFFFF0000u : 0u); v.w &= m;
    *(uint4*)(Vt + e0) = v;
}

// ---------------------------------------------------------------------------
// Fused QKV projection GEMM, m97 structure: BM=BN=128, BK=32, 4 waves.
// grid (24, 32): bx>>3 selects {Q, K, V}.
// ---------------------------------------------------------------------------
__launch_bounds__(256)
__global__ void gemm_qkv(const u16* __restrict__ A,
                         const u16* __restrict__ Wq, const u16* __restrict__ Wk,
                         const u16* __restrict__ Wv,
                         u16* __restrict__ Qh, u16* __restrict__ Kh, u16* __restrict__ Vt)
{
    __shared__ __align__(16) u16 lA[2][128 * 32];
    __shared__ __align__(16) u16 lB[2][128 * 32];
    const int tid = threadIdx.x, lane = tid & 63, w = tid >> 6;
    const int frow = lane & 15, koct = lane >> 4;
    const int sel = blockIdx.x >> 3;
    const int col0 = (blockIdx.x & 7) * 128, row0 = blockIdx.y * 128;
    const u16* B = (sel == 0) ? Wq : (sel == 1) ? Wk : Wv;
    const int wrow = (w >> 1) * 64, wcol = (w & 1) * 64;
    f32x4 acc[4][4] = {};

    auto stage = [&](int buf, int k0) {
        #pragma unroll
        for (int i = 0; i < 2; i++) {
            int p = tid + i * 256;
            int row = p >> 2, sl = p & 3, ssl = sl ^ ((row >> 1) & 3);
            gload16(A + (size_t)(row0 + row) * 1024 + k0 + ssl * 8, (char*)lA[buf] + p * 16);
        }
        #pragma unroll
        for (int i = 0; i < 2; i++) {
            int p = tid + i * 256;
            int row = p >> 2, sl = p & 3, ssl = sl ^ ((row >> 1) & 3);
            gload16(B + (size_t)(col0 + row) * 1024 + k0 + ssl * 8, (char*)lB[buf] + p * 16);
        }
    };

    stage(0, 0);
    __syncthreads();
    int buf = 0;
    for (int k0 = 0; k0 < 1024; k0 += 32) {
        if (k0 + 32 < 1024) stage(buf ^ 1, k0 + 32);
        __builtin_amdgcn_s_setprio(1);
        bf16x8 af[4], bf[4];
        #pragma unroll
        for (int i = 0; i < 4; i++) {
            int r = wrow + i * 16 + frow;
            int sl = koct ^ ((r >> 1) & 3);
            af[i] = *(const bf16x8*)((const char*)lA[buf] + r * 64 + sl * 16);
        }
        #pragma unroll
        for (int j = 0; j < 4; j++) {
            int r = wcol + j * 16 + frow;
            int sl = koct ^ ((r >> 1) & 3);
            bf[j] = *(const bf16x8*)((const char*)lB[buf] + r * 64 + sl * 16);
        }
        #pragma unroll
        for (int i = 0; i < 4; i++)
            #pragma unroll
            for (int j = 0; j < 4; j++)
                acc[i][j] = __builtin_amdgcn_mfma_f32_16x16x32_bf16(af[i], bf[j], acc[i][j], 0, 0, 0);
        __builtin_amdgcn_s_setprio(0);
        __syncthreads();
        buf ^= 1;
    }

    if (sel < 2) {
        const float scale = (sel == 0) ? 0.125f * LOG2E : 1.0f;
        u16* outp = (sel == 0) ? Qh : Kh;
        #pragma unroll
        for (int i = 0; i < 4; i++)
            #pragma unroll
            for (int j = 0; j < 4; j++)
                #pragma unroll
                for (int q = 0; q < 4; q++) {
                    int r = row0 + wrow + i * 16 + koct * 4 + q;
                    int c = col0 + wcol + j * 16 + frow;
                    float v = acc[i][j][q] * scale;
                    outp[(size_t)((c >> 6) * 4 + (r >> 10)) * 65536 +
                         (size_t)(r & 1023) * 64 + (c & 63)] = f2bf(v);
                }
    } else {
        #pragma unroll
        for (int i = 0; i < 4; i++) {
            int r0 = row0 + wrow + i * 16 + koct * 4;   // token base (mult of 4)
            #pragma unroll
            for (int j = 0; j < 4; j++) {
                int c = col0 + wcol + j * 16 + frow;    // channel
                int z = (c >> 6) * 4 + (r0 >> 10);
                uint2 pk;
                pk.x = cvt_pk_bf16(acc[i][j][0], acc[i][j][1]);
                pk.y = cvt_pk_bf16(acc[i][j][2], acc[i][j][3]);
                *(uint2*)(Vt + (size_t)z * 65536 + (size_t)(c & 63) * 1024 + (r0 & 1023)) = pk;
            }
        }
    }
}

// ---------------------------------------------------------------------------
// bf16 MFMA GEMM for FFN. MODE 2: +bias+relu bf16 out. MODE 3: +bias bf16 out.
// ---------------------------------------------------------------------------
template <int MODE>
__launch_bounds__(256)
__global__ void gemm_bt(const u16* __restrict__ A, const u16* __restrict__ B,
                        const float* __restrict__ bias, u16* __restrict__ outp)
{
    __shared__ __align__(16) u16 lA[2][128 * 64];
    __shared__ __align__(16) u16 lB[2][64 * 64];
    const int tid = threadIdx.x, lane = tid & 63, w = tid >> 6;
    const int frow = lane & 15, koct = lane >> 4;
    const int col0 = blockIdx.x * 64, row0 = blockIdx.y * 128;
    const int wrow = (w >> 1) * 64, wcol = (w & 1) * 32;
    f32x4 acc[4][2] = {};

    auto stage = [&](int buf, int k0) {
        #pragma unroll
        for (int i = 0; i < 4; i++) {
            int p = tid + i * 256;
            int row = p >> 3, sl = p & 7, ssl = sl ^ (row & 7);
            gload16(A + (size_t)(row0 + row) * 1024 + k0 + ssl * 8, (char*)lA[buf] + p * 16);
        }
        #pragma unroll
        for (int i = 0; i < 2; i++) {
            int p = tid + i * 256;
            int row = p >> 3, sl = p & 7, ssl = sl ^ (row & 7);
            gload16(B + (size_t)(col0 + row) * 1024 + k0 + ssl * 8, (char*)lB[buf] + p * 16);
        }
    };

    stage(0, 0);
    __syncthreads();
    int buf = 0;
    for (int k0 = 0; k0 < 1024; k0 += 64) {
        if (k0 + 64 < 1024) stage(buf ^ 1, k0 + 64);
        __builtin_amdgcn_s_setprio(1);
        #pragma unroll
        for (int ks = 0; ks < 2; ks++) {
            bf16x8 af[4], bf2[2];
            #pragma unroll
            for (int i = 0; i < 4; i++) {
                int r = wrow + i * 16 + frow;
                int sl = (ks * 4 + koct) ^ (r & 7);
                af[i] = *(const bf16x8*)((const char*)lA[buf] + r * 128 + sl * 16);
            }
            #pragma unroll
            for (int j = 0; j < 2; j++) {
                int r = wcol + j * 16 + frow;
                int sl = (ks * 4 + koct) ^ (r & 7);
                bf2[j] = *(const bf16x8*)((const char*)lB[buf] + r * 128 + sl * 16);
            }
            #pragma unroll
            for (int i = 0; i < 4; i++)
                #pragma unroll
                for (int j = 0; j < 2; j++)
                    acc[i][j] = __builtin_amdgcn_mfma_f32_16x16x32_bf16(af[i], bf2[j], acc[i][j], 0, 0, 0);
        }
        __builtin_amdgcn_s_setprio(0);
        __syncthreads();
        buf ^= 1;
    }

    #pragma unroll
    for (int i = 0; i < 4; i++)
        #pragma unroll
        for (int j = 0; j < 2; j++)
            #pragma unroll
            for (int q = 0; q < 4; q++) {
                int r = row0 + wrow + i * 16 + koct * 4 + q;
                int c = col0 + wcol + j * 16 + frow;
                float v = acc[i][j][q] + bias[c];
                if constexpr (MODE == 2) v = fmaxf(v, 0.f);
                outp[(size_t)r * 1024 + c] = f2bf(v);
            }
}

// ---------------------------------------------------------------------------
// Pass 1: partial[zg][n][m] = sum_{z in zg*16..+16} exp2(s'_znm) * km01(z,m)
// 1-D grid 1024, XCD-swizzled: XCD c owns one zg x 8 m-tiles.
// ---------------------------------------------------------------------------
__launch_bounds__(256)
__global__ void attn_pass1(const u16* __restrict__ Qh, const u16* __restrict__ Kh,
                           const float* __restrict__ km, float* __restrict__ partial)
{
    const int bid = blockIdx.x;
    const int mtzg = (bid & 7) * 8 + ((bid >> 3) & 7);   // cluster per XCD
    const int m0 = (mtzg & 15) * 64, zg = mtzg >> 4;
    const int n0 = (bid >> 6) * 64;

    __shared__ __align__(16) u16 lQ[2][64 * 64];
    __shared__ __align__(16) u16 lK[2][64 * 64];
    const int tid = threadIdx.x, lane = tid & 63, w = tid >> 6;
    const int frow = lane & 15, koct = lane >> 4;
    const int wn = (w >> 1) * 32, wm = (w & 1) * 32;
    f32x4 ssum[2][2] = {};

    auto stage = [&](int buf, int z) {
        #pragma unroll
        for (int i = 0; i < 2; i++) {
            int p = tid + i * 256;
            int row = p >> 3, sl = p & 7, ssl = sl ^ (row & 7);
            gload16(Qh + (size_t)(z * NSEQ + n0 + row) * 64 + ssl * 8, (char*)lQ[buf] + p * 16);
            gload16(Kh + (size_t)(z * NSEQ + m0 + row) * 64 + ssl * 8, (char*)lK[buf] + p * 16);
        }
    };

    const int z0 = zg * 16;
    stage(0, z0);
    __syncthreads();
    int buf = 0;
    for (int zi = 0; zi < 16; zi++) {
        const int z = z0 + zi;
        if (zi < 15) stage(buf ^ 1, z + 1);
        f32x4 km4[2];
        #pragma unroll
        for (int j = 0; j < 2; j++)
            km4[j] = *(const f32x4*)(km + z * NSEQ + m0 + wm + j * 16 + koct * 4);
        f32x4 s[2][2] = {};
        __builtin_amdgcn_s_setprio(1);
        #pragma unroll
        for (int ks = 0; ks < 2; ks++) {
            bf16x8 a[2], b2[2];
            #pragma unroll
            for (int i = 0; i < 2; i++) {
                int r = wn + i * 16 + frow;
                int sl = (ks * 4 + koct) ^ (r & 7);
                a[i] = *(const bf16x8*)((const char*)lQ[buf] + r * 128 + sl * 16);
            }
            #pragma unroll
            for (int j = 0; j < 2; j++) {
                int r = wm + j * 16 + frow;
                int sl = (ks * 4 + koct) ^ (r & 7);
                b2[j] = *(const bf16x8*)((const char*)lK[buf] + r * 128 + sl * 16);
            }
            #pragma unroll
            for (int i = 0; i < 2; i++)
                #pragma unroll
                for (int j = 0; j < 2; j++)
                    s[i][j] = __builtin_amdgcn_mfma_f32_16x16x32_bf16(b2[j], a[i], s[i][j], 0, 0, 0);
        }
        __builtin_amdgcn_s_setprio(0);
        #pragma unroll
        for (int j = 0; j < 2; j++)
            #pragma unroll
            for (int i = 0; i < 2; i++)
                #pragma unroll
                for (int q = 0; q < 4; q++)
                    ssum[i][j][q] += __builtin_amdgcn_exp2f(s[i][j][q]) * km4[j][q];
        __syncthreads();
        buf ^= 1;
    }
    #pragma unroll
    for (int i = 0; i < 2; i++)
        #pragma unroll
        for (int j = 0; j < 2; j++) {
            int ng = n0 + wn + i * 16 + frow;
            int mg = m0 + wm + j * 16 + koct * 4;
            *(f32x4*)(partial + (size_t)zg * 1048576 + (size_t)ng * NSEQ + mg) = ssum[i][j];
        }
}

// invS = 1 / (p0+p1+p2+p3)
__launch_bounds__(256)
__global__ void sum_inv(const float* __restrict__ p, float* __restrict__ invS) {
    int i = (blockIdx.x * 256 + threadIdx.x) * 4;
    float4 a = *(const float4*)(p + i);
    float4 b = *(const float4*)(p + 1048576 + i);
    float4 c = *(const float4*)(p + 2097152 + i);
    float4 d = *(const float4*)(p + 3145728 + i);
    float4 r;
    float s;
    s = a.x + b.x + c.x + d.x; r.x = s > 0.f ? 1.f / s : 0.f;
    s = a.y + b.y + c.y + d.y; r.y = s > 0.f ? 1.f / s : 0.f;
    s = a.z + b.z + c.z + d.z; r.z = s > 0.f ? 1.f / s : 0.f;
    s = a.w + b.w + c.w + d.w; r.w = s > 0.f ? 1.f / s : 0.f;
    *(float4*)(invS + i) = r;
}

// ---------------------------------------------------------------------------
// Pass 2 (R7 structure, bf16 output): per z, out = sum_m (exp2(s')*invS) V'[m,:]
// m-tile 64, double-buffered staging, wave-private lP, 1 barrier per tile.
// grid 1024, XCD c owns z in {8c..8c+7}.
// ---------------------------------------------------------------------------
__launch_bounds__(256)
__global__ void attn_pass2(const u16* __restrict__ Qh, const u16* __restrict__ Kh,
                           const u16* __restrict__ Vt,
                           const float* __restrict__ qm, const float* __restrict__ invS,
                           const u8* __restrict__ pad, u16* __restrict__ attn)
{
    const int bid = blockIdx.x;
    const int z  = (bid & 7) * 8 + ((bid >> 3) & 7);     // cluster per XCD
    const int n0 = (bid >> 6) * 64;

    __shared__ __align__(16) u16 lK[2][64 * 64];
    __shared__ __align__(16) u16 lV[2][64 * 64];   // Vt tile: [d][m]
    __shared__ __align__(16) u16 lP[64 * 64];
    const int tid = threadIdx.x, lane = tid & 63, w = tid >> 6;
    const int frow = lane & 15, koct = lane >> 4;
    const int hh = z >> 2, bb = z & 3;
    const int wrow = w * 16;
    const int nl_row = wrow + frow;
    const size_t inv_base = (size_t)(n0 + nl_row) * NSEQ;

    bf16x8 aq[2];
    #pragma unroll
    for (int ks = 0; ks < 2; ks++)
        aq[ks] = *(const bf16x8*)(Qh + (size_t)(z * NSEQ + n0 + nl_row) * 64 + ks * 32 + koct * 8);

    auto stage = [&](int buf, int m0) {
        #pragma unroll
        for (int i = 0; i < 2; i++) {
            int p = tid + i * 256;
            int row = p >> 3, sl = p & 7, ssl = sl ^ (row & 7);
            gload16(Kh + (size_t)(z * NSEQ + m0 + row) * 64 + ssl * 8, (char*)lK[buf] + p * 16);
            gload16(Vt + (size_t)z * 65536 + (size_t)row * 1024 + m0 + ssl * 8, (char*)lV[buf] + p * 16);
        }
    };

    f32x4 oacc[4] = {};
    f32x4 iv[4];
    #pragma unroll
    for (int j = 0; j < 4; j++)
        iv[j] = *(const f32x4*)(invS + inv_base + j * 16 + koct * 4);
    stage(0, 0);
    __syncthreads();
    int buf = 0;

    for (int mt = 0; mt < 16; mt++) {
        const int m0 = mt * 64;
        if (mt < 15) stage(buf ^ 1, m0 + 64);
        f32x4 ivn[4];
        if (mt < 15) {
            #pragma unroll
            for (int j = 0; j < 4; j++)
                ivn[j] = *(const f32x4*)(invS + inv_base + m0 + 64 + j * 16 + koct * 4);
        }
        f32x4 s[4] = {};
        __builtin_amdgcn_s_setprio(1);
        #pragma unroll
        for (int ks = 0; ks < 2; ks++) {
            bf16x8 kb[4];
            #pragma unroll
            for (int j = 0; j < 4; j++) {
                int r = j * 16 + frow;
                int sl = (ks * 4 + koct) ^ (r & 7);
                kb[j] = *(const bf16x8*)((const char*)lK[buf] + r * 128 + sl * 16);
            }
            #pragma unroll
            for (int j = 0; j < 4; j++)
                s[j] = __builtin_amdgcn_mfma_f32_16x16x32_bf16(kb[j], aq[ks], s[j], 0, 0, 0);
        }
        __builtin_amdgcn_s_setprio(0);
        #pragma unroll
        for (int j = 0; j < 4; j++) {
            float p0 = __builtin_amdgcn_exp2f(s[j][0]) * iv[j][0];
            float p1 = __builtin_amdgcn_exp2f(s[j][1]) * iv[j][1];
            float p2 = __builtin_amdgcn_exp2f(s[j][2]) * iv[j][2];
            float p3 = __builtin_amdgcn_exp2f(s[j][3]) * iv[j][3];
            uint2 pk;
            pk.x = cvt_pk_bf16(p0, p1);
            pk.y = cvt_pk_bf16(p2, p3);
            int slot = (j * 2 + (koct >> 1)) ^ (nl_row & 7);
            *(uint2*)((char*)lP + nl_row * 128 + slot * 16 + (koct & 1) * 8) = pk;
        }
        __builtin_amdgcn_s_setprio(1);
        #pragma unroll
        for (int ks = 0; ks < 2; ks++) {
            int sl = (ks * 4 + koct) ^ (nl_row & 7);
            bf16x8 pa = *(const bf16x8*)((const char*)lP + nl_row * 128 + sl * 16);
            bf16x8 vb[4];
            #pragma unroll
            for (int dj = 0; dj < 4; dj++) {
                int rr = dj * 16 + frow;
                int sv = (ks * 4 + koct) ^ (rr & 7);
                vb[dj] = *(const bf16x8*)((const char*)lV[buf] + rr * 128 + sv * 16);
            }
            #pragma unroll
            for (int dj = 0; dj < 4; dj++)
                oacc[dj] = __builtin_amdgcn_mfma_f32_16x16x32_bf16(pa, vb[dj], oacc[dj], 0, 0, 0);
        }
        __builtin_amdgcn_s_setprio(0);
        __syncthreads();
        buf ^= 1;
        #pragma unroll
        for (int j = 0; j < 4; j++) iv[j] = ivn[j];
    }

    #pragma unroll
    for (int q = 0; q < 4; q++) {
        int ns = n0 + wrow + koct * 4 + q;
        float f = qm[z * NSEQ + ns] * (pad[bb * NSEQ + ns] ? 0.f : 1.f);
        #pragma unroll
        for (int dj = 0; dj < 4; dj++) {
            int d = dj * 16 + frow;
            attn[(size_t)(bb * NSEQ + ns) * DMODEL + hh * 64 + d] = f2bf(oacc[dj][q] * f);
        }
    }
}

// ---------------------------------------------------------------------------
// LayerNorm over last dim (1024), one block per row.
// MODE 0: A f32 + B bf16 -> v = a+b ; out bf16 (hb) only.
// MODE 1: A bf16, B bf16 -> v = a*valid + b ; out f32 * valid (final).
// ---------------------------------------------------------------------------
template <int MODE>
__launch_bounds__(256)
__global__ void ln_kernel(const void* __restrict__ Ap, const void* __restrict__ Bp,
                          const float* __restrict__ g, const float* __restrict__ beta,
                          const u8* __restrict__ pad,
                          float* __restrict__ outf, u16* __restrict__ outb)
{
    const int row = blockIdx.x, tid = threadIdx.x;
    const int lane = tid & 63, wv = tid >> 6;
    const float valid = pad[row] ? 0.f : 1.f;
    __shared__ float red[4];

    float v[4];
    if constexpr (MODE == 0) {
        float4 va = *(const float4*)((const float*)Ap + (size_t)row * 1024 + tid * 4);
        uint2 bbv = *(const uint2*)((const u16*)Bp + (size_t)row * 1024 + tid * 4);
        v[0] = va.x + bf2f(bbv.x & 0xFFFFu);
        v[1] = va.y + bf2f(bbv.x >> 16);
        v[2] = va.z + bf2f(bbv.y & 0xFFFFu);
        v[3] = va.w + bf2f(bbv.y >> 16);
    } else {
        uint2 aav = *(const uint2*)((const u16*)Ap + (size_t)row * 1024 + tid * 4);
        uint2 bbv = *(const uint2*)((const u16*)Bp + (size_t)row * 1024 + tid * 4);
        v[0] = bf2f(aav.x & 0xFFFFu) * valid + bf2f(bbv.x & 0xFFFFu);
        v[1] = bf2f(aav.x >> 16)     * valid + bf2f(bbv.x >> 16);
        v[2] = bf2f(aav.y & 0xFFFFu) * valid + bf2f(bbv.y & 0xFFFFu);
        v[3] = bf2f(aav.y >> 16)     * valid + bf2f(bbv.y >> 16);
    }
    float s = v[0] + v[1] + v[2] + v[3];
    #pragma unroll
    for (int off = 32; off > 0; off >>= 1) s += __shfl_down(s, off, 64);
    if (lane == 0) red[wv] = s;
    __syncthreads();
    float mean = (red[0] + red[1] + red[2] + red[3]) * (1.f / 1024.f);
    float sq = 0.f;
    #pragma unroll
    for (int k = 0; k < 4; k++) { float d = v[k] - mean; sq += d * d; }
    __syncthreads();
    #pragma unroll
    for (int off = 32; off > 0; off >>= 1) sq += __shfl_down(sq, off, 64);
    if (lane == 0) red[wv] = sq;
    __syncthreads();
    float var = (red[0] + red[1] + red[2] + red[3]) * (1.f / 1024.f);
    float rstd = rsqrtf(var + 1e-5f);

    if constexpr (MODE == 0) {
        uint2 o;
        float o0 = (v[0] - mean) * rstd * g[tid * 4 + 0] + beta[tid * 4 + 0];
        float o1 = (v[1] - mean) * rstd * g[tid * 4 + 1] + beta[tid * 4 + 1];
        float o2 = (v[2] - mean) * rstd * g[tid * 4 + 2] + beta[tid * 4 + 2];
        float o3 = (v[3] - mean) * rstd * g[tid * 4 + 3] + beta[tid * 4 + 3];
        o.x = cvt_pk_bf16(o0, o1);
        o.y = cvt_pk_bf16(o2, o3);
        *(uint2*)(outb + (size_t)row * 1024 + tid * 4) = o;
    } else {
        float4 o;
        o.x = ((v[0] - mean) * rstd * g[tid * 4 + 0] + beta[tid * 4 + 0]) * valid;
        o.y = ((v[1] - mean) * rstd * g[tid * 4 + 1] + beta[tid * 4 + 1]) * valid;
        o.z = ((v[2] - mean) * rstd * g[tid * 4 + 2] + beta[tid * 4 + 2]) * valid;
        o.w = ((v[3] - mean) * rstd * g[tid * 4 + 3] + beta[tid * 4 + 3]) * valid;
        *(float4*)(outf + (size_t)row * 1024 + tid * 4) = o;
    }
}

// ---------------------------------------------------------------------------
extern "C" void kernel_launch(void* const* d_in, const int* in_sizes, int n_in,
                              void* d_out, int out_size, void* d_ws, size_t ws_size,
                              hipStream_t stream)
{
    const float* x   = (const float*)d_in[0];
    const u8*    pad = (const u8*)d_in[1];
    const float* Wq  = (const float*)d_in[2];
    const float* Wk  = (const float*)d_in[3];
    const float* Wv  = (const float*)d_in[4];
    const float* W1  = (const float*)d_in[5];
    const float* b1  = (const float*)d_in[6];
    const float* W2  = (const float*)d_in[7];
    const float* b2  = (const float*)d_in[8];
    const float* g1  = (const float*)d_in[9];
    const float* be1 = (const float*)d_in[10];
    const float* g2  = (const float*)d_in[11];
    const float* be2 = (const float*)d_in[12];
    float* out = (float*)d_out;

    // workspace (~95 MB)
    u16* xb    = (u16*)d_ws;
    u16* Wqb   = xb    + 4194304;
    u16* Wkb   = Wqb   + 1048576;
    u16* Wvb   = Wkb   + 1048576;
    u16* W1b   = Wvb   + 1048576;
    u16* W2b   = W1b   + 1048576;
    u16* Qh    = W2b   + 1048576;        // [z][n][dh]
    u16* Kh    = Qh    + 4194304;        // [z][n][dh]
    u16* Vt    = Kh    + 4194304;        // [z][dh][n]  (km applied by vt_km)
    u16* hb    = Vt    + 4194304;        // LN1 output, bf16
    u16* ff1b  = hb    + 4194304;
    u16* ffb   = ff1b  + 4194304;        // FFN2 output, bf16
    u16* attnb = ffb   + 4194304;        // attention output, bf16
    float* km      = (float*)(attnb + 4194304);
    float* qm      = km      + 65536;
    float* partial = qm      + 65536;           // 4M f32
    float* invS    = partial + 4194304;         // 1M f32

    P5 p5;
    p5.in[0] = Wq; p5.in[1] = Wk; p5.in[2] = Wv; p5.in[3] = W1; p5.in[4] = W2;
    p5.out[0] = Wqb; p5.out[1] = Wkb; p5.out[2] = Wvb; p5.out[3] = W1b; p5.out[4] = W2b;
    cvt_all<<<9216, 256, 0, stream>>>(x, xb, p5);

    // fused Q/K/V projections, m97-structure 128x128 tiles
    gemm_qkv<<<dim3(24, 32), 256, 0, stream>>>(xb, Wqb, Wkb, Wvb, Qh, Kh, Vt);

    rowmask2_bf<<<512, 256, 0, stream>>>(Kh, Qh, km, qm);
    vt_km<<<4096, 256, 0, stream>>>(Vt, km);

    attn_pass1<<<1024, 256, 0, stream>>>(Qh, Kh, km, partial);
    sum_inv<<<1024, 256, 0, stream>>>(partial, invS);
    attn_pass2<<<1024, 256, 0, stream>>>(Qh, Kh, Vt, qm, invS, pad, attnb);

    // h = LN(x + attn) -> bf16 only
    ln_kernel<0><<<4096, 256, 0, stream>>>(x, attnb, g1, be1, pad, nullptr, hb);

    // FFN (both outputs bf16)
    gemm_bt<2><<<dim3(16, 32), 256, 0, stream>>>(hb,   W1b, b1, ff1b);
    gemm_bt<3><<<dim3(16, 32), 256, 0, stream>>>(ff1b, W2b, b2, ffb);

    // out = LN(ff*valid + h) * valid  (final f32)
    ln_kernel<1><<<4096, 256, 0, stream>>>(ffb, hb, g2, be2, pad, out, nullptr);
}